// Round 1
// baseline (851.103 us; speedup 1.0000x reference)
//
#include <hip/hip_runtime.h>

#define DIN 128
#define HID 128
#define DOUT 64
#define SCAN_B 1024

static inline int ceil_div(int a, int b) { return (a + b - 1) / b; }

// ---------------- CSR build ----------------

__global__ void k_hist(const int* __restrict__ dst, int E, int* __restrict__ count) {
  int i = blockIdx.x * blockDim.x + threadIdx.x;
  if (i < E) atomicAdd(&count[dst[i]], 1);
}

// Inclusive scan of `in[0..n)` -> incl[0..n); per-block totals -> bsum[block].
__global__ __launch_bounds__(SCAN_B) void k_scan1(const int* __restrict__ in, int n,
                                                  int* __restrict__ incl,
                                                  int* __restrict__ bsum) {
  __shared__ int ws[SCAN_B / 64];
  int t = threadIdx.x;
  int i = blockIdx.x * SCAN_B + t;
  int lane = t & 63, w = t >> 6;
  int v = (i < n) ? in[i] : 0;
#pragma unroll
  for (int d = 1; d < 64; d <<= 1) {
    int u = __shfl_up(v, d, 64);
    if (lane >= d) v += u;
  }
  if (lane == 63) ws[w] = v;
  __syncthreads();
  if (w == 0) {
    int s = (lane < SCAN_B / 64) ? ws[lane] : 0;
#pragma unroll
    for (int d = 1; d < SCAN_B / 64; d <<= 1) {
      int u = __shfl_up(s, d, 64);
      if (lane >= d) s += u;
    }
    if (lane < SCAN_B / 64) ws[lane] = s;
  }
  __syncthreads();
  if (w > 0) v += ws[w - 1];
  if (i < n) incl[i] = v;
  if (t == SCAN_B - 1) bsum[blockIdx.x] = v;
}

// Finalize: row_ptr[i+1] = incl + block offset; cursor[i] = row_ptr[i]; dinv.
__global__ void k_scan3(const int* __restrict__ count, int n,
                        const int* __restrict__ bsum_incl,
                        int* __restrict__ row_ptr,  // incl partials already at row_ptr+1
                        int* __restrict__ cursor, float* __restrict__ dinv) {
  int i = blockIdx.x * blockDim.x + threadIdx.x;
  if (i < n) {
    int b = i >> 10;
    int v = row_ptr[i + 1] + (b > 0 ? bsum_incl[b - 1] : 0);
    row_ptr[i + 1] = v;
    int c = count[i];
    cursor[i] = v - c;
    dinv[i] = rsqrtf((float)c + 1.0f);  // +1 = self-loop
    if (i == 0) row_ptr[0] = 0;
  }
}

__global__ void k_scatter(const int* __restrict__ src, const int* __restrict__ dst, int E,
                          const float* __restrict__ dinv, int* __restrict__ cursor,
                          int* __restrict__ csr_src, float* __restrict__ csr_w) {
  int i = blockIdx.x * blockDim.x + threadIdx.x;
  if (i < E) {
    int s = src[i];
    int d = dst[i];
    int p = atomicAdd(&cursor[d], 1);
    csr_src[p] = s;
    csr_w[p] = dinv[s];
  }
}

// ---------------- GEMM 1: xW = x @ W1  (N x 128) @ (128 x 128) ----------------

__global__ __launch_bounds__(256) void k_gemm1(const float* __restrict__ A,
                                               const float* __restrict__ W,
                                               float* __restrict__ C, int n) {
  __shared__ float xs[64 * 129];
  int t = threadIdx.x;
  int r0 = blockIdx.x * 64;
  for (int f = t; f < 64 * 32; f += 256) {
    int row = f >> 5;
    int col = (f & 31) << 2;
    int gr = r0 + row;
    float4 v = make_float4(0.f, 0.f, 0.f, 0.f);
    if (gr < n) v = *(const float4*)(A + (size_t)gr * DIN + col);
    float* p = &xs[row * 129 + col];
    p[0] = v.x; p[1] = v.y; p[2] = v.z; p[3] = v.w;
  }
  __syncthreads();
  int r = t & 63, q = t >> 6;  // lane = row, wave = col quarter
  float acc[32];
#pragma unroll
  for (int j = 0; j < 32; j++) acc[j] = 0.f;
  const float* Wq = W + q * 32;
#pragma unroll 4
  for (int k = 0; k < DIN; k++) {
    float xk = xs[r * 129 + k];
#pragma unroll
    for (int j4 = 0; j4 < 8; j4++) {
      float4 w = *(const float4*)(Wq + k * HID + j4 * 4);
      acc[j4 * 4 + 0] += xk * w.x;
      acc[j4 * 4 + 1] += xk * w.y;
      acc[j4 * 4 + 2] += xk * w.z;
      acc[j4 * 4 + 3] += xk * w.w;
    }
  }
  int gr = r0 + r;
  if (gr < n) {
    float* Cp = C + (size_t)gr * HID + q * 32;
#pragma unroll
    for (int j4 = 0; j4 < 8; j4++)
      *(float4*)(Cp + j4 * 4) =
          make_float4(acc[j4 * 4], acc[j4 * 4 + 1], acc[j4 * 4 + 2], acc[j4 * 4 + 3]);
  }
}

// ------------- Aggregation: out[n] = sum_{e: dst=n} dinv[n]*dinv[src]*H[src] + dinv[n]^2*H[n]
// one wave per node, lane owns a float2 column pair -------------

__global__ __launch_bounds__(256) void k_agg(const float* __restrict__ H,
                                             const int* __restrict__ row_ptr,
                                             const int* __restrict__ csr_src,
                                             const float* __restrict__ csr_w,
                                             const float* __restrict__ dinv,
                                             const float* __restrict__ bias,
                                             float* __restrict__ out, int n, int relu) {
  int wave = (blockIdx.x * blockDim.x + threadIdx.x) >> 6;
  int lane = threadIdx.x & 63;
  if (wave >= n) return;
  float dn = dinv[wave];
  int beg = row_ptr[wave], end = row_ptr[wave + 1];
  float2 hv = ((const float2*)(H + (size_t)wave * HID))[lane];
  float wself = dn * dn;
  float ax = wself * hv.x, ay = wself * hv.y;
  int j = beg;
  for (; j + 1 < end; j += 2) {
    int s0 = csr_src[j], s1 = csr_src[j + 1];
    float w0 = dn * csr_w[j], w1 = dn * csr_w[j + 1];
    float2 v0 = ((const float2*)(H + (size_t)s0 * HID))[lane];
    float2 v1 = ((const float2*)(H + (size_t)s1 * HID))[lane];
    ax += w0 * v0.x;
    ay += w0 * v0.y;
    ax += w1 * v1.x;
    ay += w1 * v1.y;
  }
  if (j < end) {
    int s = csr_src[j];
    float w = dn * csr_w[j];
    float2 v = ((const float2*)(H + (size_t)s * HID))[lane];
    ax += w * v.x;
    ay += w * v.y;
  }
  if (bias) {
    ax += bias[2 * lane];
    ay += bias[2 * lane + 1];
  }
  if (relu) {
    ax = fmaxf(ax, 0.f);
    ay = fmaxf(ay, 0.f);
  }
  ((float2*)(out + (size_t)wave * HID))[lane] = make_float2(ax, ay);
}

// ------------- Final GEMM (fused): mu = agg2@Wmu + bmu ; ls = agg2@Wls + bls -------------

__global__ __launch_bounds__(256) void k_gemm2(const float* __restrict__ A,
                                               const float* __restrict__ Wmu,
                                               const float* __restrict__ bmu,
                                               const float* __restrict__ Wls,
                                               const float* __restrict__ bls,
                                               float* __restrict__ out, int n) {
  __shared__ float xs[64 * 129];
  int t = threadIdx.x;
  int r0 = blockIdx.x * 64;
  for (int f = t; f < 64 * 32; f += 256) {
    int row = f >> 5;
    int col = (f & 31) << 2;
    int gr = r0 + row;
    float4 v = make_float4(0.f, 0.f, 0.f, 0.f);
    if (gr < n) v = *(const float4*)(A + (size_t)gr * HID + col);
    float* p = &xs[row * 129 + col];
    p[0] = v.x; p[1] = v.y; p[2] = v.z; p[3] = v.w;
  }
  __syncthreads();
  int r = t & 63, q = t >> 6;                 // q 0,1 -> mu; 2,3 -> logstd
  const float* Wsel = (q < 2) ? Wmu : Wls;
  const float* bsel = (q < 2) ? bmu : bls;
  int c0 = (q & 1) * 32;
  float acc[32];
#pragma unroll
  for (int j = 0; j < 32; j++) acc[j] = 0.f;
#pragma unroll 4
  for (int k = 0; k < HID; k++) {
    float xk = xs[r * 129 + k];
#pragma unroll
    for (int j4 = 0; j4 < 8; j4++) {
      float4 w = *(const float4*)(Wsel + k * DOUT + c0 + j4 * 4);
      acc[j4 * 4 + 0] += xk * w.x;
      acc[j4 * 4 + 1] += xk * w.y;
      acc[j4 * 4 + 2] += xk * w.z;
      acc[j4 * 4 + 3] += xk * w.w;
    }
  }
  int gr = r0 + r;
  if (gr < n) {
    float* op = out + ((q < 2) ? (size_t)0 : (size_t)n * DOUT) + (size_t)gr * DOUT + c0;
#pragma unroll
    for (int j4 = 0; j4 < 8; j4++) {
      float4 vv = make_float4(acc[j4 * 4 + 0] + bsel[c0 + j4 * 4 + 0],
                              acc[j4 * 4 + 1] + bsel[c0 + j4 * 4 + 1],
                              acc[j4 * 4 + 2] + bsel[c0 + j4 * 4 + 2],
                              acc[j4 * 4 + 3] + bsel[c0 + j4 * 4 + 3]);
      *(float4*)(op + j4 * 4) = vv;
    }
  }
}

// ---------------- launcher ----------------

extern "C" void kernel_launch(void* const* d_in, const int* in_sizes, int n_in,
                              void* d_out, int out_size, void* d_ws, size_t ws_size,
                              hipStream_t stream) {
  const float* x   = (const float*)d_in[0];
  const int*   ei  = (const int*)d_in[1];
  const float* W1  = (const float*)d_in[2];
  const float* b1  = (const float*)d_in[3];
  const float* Wmu = (const float*)d_in[4];
  const float* bmu = (const float*)d_in[5];
  const float* Wls = (const float*)d_in[6];
  const float* bls = (const float*)d_in[7];
  float* out = (float*)d_out;

  const int N = in_sizes[0] / DIN;
  const int E = in_sizes[1] / 2;
  const int* esrc = ei;
  const int* edst = ei + E;

  char* ws = (char*)d_ws;
  size_t off = 0;
  auto alloc = [&](size_t bytes) -> void* {
    void* p = ws + off;
    off = (off + bytes + 255) & ~(size_t)255;
    return p;
  };
  float* xW    = (float*)alloc((size_t)N * HID * sizeof(float));  // reused as agg2
  float* h     = (float*)alloc((size_t)N * HID * sizeof(float));
  int* count   = (int*)alloc((size_t)N * 4);
  int* row_ptr = (int*)alloc((size_t)(N + 1) * 4);
  int* cursor  = (int*)alloc((size_t)N * 4);
  int* csr_src = (int*)alloc((size_t)E * 4);
  float* csr_w = (float*)alloc((size_t)E * 4);
  float* dinv  = (float*)alloc((size_t)N * 4);
  const int nb = ceil_div(N, SCAN_B);
  int* bsum    = (int*)alloc((size_t)(nb + 1) * 4);
  int* bdummy  = (int*)alloc(64);
  (void)ws_size; (void)n_in; (void)out_size;

  // CSR build
  hipMemsetAsync(count, 0, (size_t)N * 4, stream);
  k_hist<<<ceil_div(E, 256), 256, 0, stream>>>(edst, E, count);
  k_scan1<<<nb, SCAN_B, 0, stream>>>(count, N, row_ptr + 1, bsum);
  k_scan1<<<1, SCAN_B, 0, stream>>>(bsum, nb, bsum, bdummy);  // in-place scan of block sums
  k_scan3<<<ceil_div(N, 256), 256, 0, stream>>>(count, N, bsum, row_ptr, cursor, dinv);
  k_scatter<<<ceil_div(E, 256), 256, 0, stream>>>(esrc, edst, E, dinv, cursor, csr_src, csr_w);

  // Layer 1: h = relu(Ahat @ (x@W1) + b1)
  k_gemm1<<<ceil_div(N, 64), 256, 0, stream>>>(x, W1, xW, N);
  k_agg<<<ceil_div(N, 4), 256, 0, stream>>>(xW, row_ptr, csr_src, csr_w, dinv, b1, h, N, 1);

  // Layer 2+3: agg2 = Ahat @ h (once), then mu/logstd = agg2 @ W + b
  k_agg<<<ceil_div(N, 4), 256, 0, stream>>>(h, row_ptr, csr_src, csr_w, dinv, nullptr, xW, N, 0);
  k_gemm2<<<ceil_div(N, 64), 256, 0, stream>>>(xW, Wmu, bmu, Wls, bls, out, N);
}

// Round 2
// 565.929 us; speedup vs baseline: 1.5039x; 1.5039x over previous
//
#include <hip/hip_runtime.h>

#define DIN 128
#define HID 128
#define DOUT 64
#define SCAN_B 1024

static inline int ceil_div(int a, int b) { return (a + b - 1) / b; }

// ---------------- CSR build ----------------

__global__ void k_hist(const int* __restrict__ dst, int E, int* __restrict__ count) {
  int i = blockIdx.x * blockDim.x + threadIdx.x;
  if (i < E) atomicAdd(&count[dst[i]], 1);
}

// Inclusive scan of `in[0..n)` -> incl[0..n); per-block totals -> bsum[block].
__global__ __launch_bounds__(SCAN_B) void k_scan1(const int* __restrict__ in, int n,
                                                  int* __restrict__ incl,
                                                  int* __restrict__ bsum) {
  __shared__ int ws[SCAN_B / 64];
  int t = threadIdx.x;
  int i = blockIdx.x * SCAN_B + t;
  int lane = t & 63, w = t >> 6;
  int v = (i < n) ? in[i] : 0;
#pragma unroll
  for (int d = 1; d < 64; d <<= 1) {
    int u = __shfl_up(v, d, 64);
    if (lane >= d) v += u;
  }
  if (lane == 63) ws[w] = v;
  __syncthreads();
  if (w == 0) {
    int s = (lane < SCAN_B / 64) ? ws[lane] : 0;
#pragma unroll
    for (int d = 1; d < SCAN_B / 64; d <<= 1) {
      int u = __shfl_up(s, d, 64);
      if (lane >= d) s += u;
    }
    if (lane < SCAN_B / 64) ws[lane] = s;
  }
  __syncthreads();
  if (w > 0) v += ws[w - 1];
  if (i < n) incl[i] = v;
  if (t == SCAN_B - 1) bsum[blockIdx.x] = v;
}

// Finalize: row_ptr[i+1] = incl + block offset; cursor[i] = row_ptr[i]; dinv.
__global__ void k_scan3(const int* __restrict__ count, int n,
                        const int* __restrict__ bsum_incl,
                        int* __restrict__ row_ptr,  // incl partials already at row_ptr+1
                        int* __restrict__ cursor, float* __restrict__ dinv) {
  int i = blockIdx.x * blockDim.x + threadIdx.x;
  if (i < n) {
    int b = i >> 10;
    int v = row_ptr[i + 1] + (b > 0 ? bsum_incl[b - 1] : 0);
    row_ptr[i + 1] = v;
    int c = count[i];
    cursor[i] = v - c;
    dinv[i] = rsqrtf((float)c + 1.0f);  // +1 = self-loop
    if (i == 0) row_ptr[0] = 0;
  }
}

__global__ void k_scatter(const int* __restrict__ src, const int* __restrict__ dst, int E,
                          const float* __restrict__ dinv, int* __restrict__ cursor,
                          int* __restrict__ csr_src, float* __restrict__ csr_w) {
  int i = blockIdx.x * blockDim.x + threadIdx.x;
  if (i < E) {
    int s = src[i];
    int d = dst[i];
    int p = atomicAdd(&cursor[d], 1);
    csr_src[p] = s;
    csr_w[p] = dinv[s];
  }
}

// ---------------- GEMM 1: xW = x @ W1  (N x 128) @ (128 x 128) ----------------
// 128x128 tile / block of 256 threads; 8x8 micro-tile per thread; A & W staged in LDS.

__global__ __launch_bounds__(256) void k_gemm1(const float* __restrict__ A,
                                               const float* __restrict__ W,
                                               float* __restrict__ C, int n) {
  __shared__ float at[32][132];  // k-major transposed A tile (pad keeps 16B align, spreads banks)
  __shared__ float wt[32][128];  // k-major W tile (natural layout)
  int t = threadIdx.x;
  int r0b = blockIdx.x * 128;
  int tr = t >> 4, tc = t & 15;
  int ra = tr * 8, ca = tc * 8;
  float acc[8][8];
#pragma unroll
  for (int i = 0; i < 8; i++)
#pragma unroll
    for (int j = 0; j < 8; j++) acc[i][j] = 0.f;

  for (int k0 = 0; k0 < DIN; k0 += 32) {
    __syncthreads();
#pragma unroll
    for (int i = 0; i < 4; i++) {
      int c = t + 256 * i;
      int row = c >> 3;        // 0..127
      int kc = (c & 7) * 4;    // 0..28
      int gr = r0b + row;
      float4 v = make_float4(0.f, 0.f, 0.f, 0.f);
      if (gr < n) v = *(const float4*)(A + (size_t)gr * DIN + k0 + kc);
      at[kc + 0][row] = v.x;
      at[kc + 1][row] = v.y;
      at[kc + 2][row] = v.z;
      at[kc + 3][row] = v.w;
    }
#pragma unroll
    for (int i = 0; i < 4; i++) {
      int c = t + 256 * i;
      int kr = c >> 5;          // 0..31
      int kc = (c & 31) * 4;    // 0..124
      *(float4*)&wt[kr][kc] = *(const float4*)(W + (size_t)(k0 + kr) * HID + kc);
    }
    __syncthreads();
#pragma unroll
    for (int k = 0; k < 32; k++) {
      float a[8], w[8];
      *(float4*)&a[0] = *(float4*)&at[k][ra];
      *(float4*)&a[4] = *(float4*)&at[k][ra + 4];
      *(float4*)&w[0] = *(float4*)&wt[k][ca];
      *(float4*)&w[4] = *(float4*)&wt[k][ca + 4];
#pragma unroll
      for (int i = 0; i < 8; i++)
#pragma unroll
        for (int j = 0; j < 8; j++) acc[i][j] += a[i] * w[j];
    }
  }
#pragma unroll
  for (int i = 0; i < 8; i++) {
    int gr = r0b + ra + i;
    if (gr < n) {
      float* p = C + (size_t)gr * HID + ca;
      *(float4*)p = make_float4(acc[i][0], acc[i][1], acc[i][2], acc[i][3]);
      *(float4*)(p + 4) = make_float4(acc[i][4], acc[i][5], acc[i][6], acc[i][7]);
    }
  }
}

// ------------- Aggregation: out[n] = sum_{e: dst=n} dinv[n]*dinv[src]*H[src] + dinv[n]^2*H[n]
// one wave per node, lane owns a float2 column pair -------------

__global__ __launch_bounds__(256) void k_agg(const float* __restrict__ H,
                                             const int* __restrict__ row_ptr,
                                             const int* __restrict__ csr_src,
                                             const float* __restrict__ csr_w,
                                             const float* __restrict__ dinv,
                                             const float* __restrict__ bias,
                                             float* __restrict__ out, int n, int relu) {
  int wave = (blockIdx.x * blockDim.x + threadIdx.x) >> 6;
  int lane = threadIdx.x & 63;
  if (wave >= n) return;
  float dn = dinv[wave];
  int beg = row_ptr[wave], end = row_ptr[wave + 1];
  float2 hv = ((const float2*)(H + (size_t)wave * HID))[lane];
  float wself = dn * dn;
  float ax = wself * hv.x, ay = wself * hv.y;
  int j = beg;
  for (; j + 1 < end; j += 2) {
    int s0 = csr_src[j], s1 = csr_src[j + 1];
    float w0 = dn * csr_w[j], w1 = dn * csr_w[j + 1];
    float2 v0 = ((const float2*)(H + (size_t)s0 * HID))[lane];
    float2 v1 = ((const float2*)(H + (size_t)s1 * HID))[lane];
    ax += w0 * v0.x;
    ay += w0 * v0.y;
    ax += w1 * v1.x;
    ay += w1 * v1.y;
  }
  if (j < end) {
    int s = csr_src[j];
    float w = dn * csr_w[j];
    float2 v = ((const float2*)(H + (size_t)s * HID))[lane];
    ax += w * v.x;
    ay += w * v.y;
  }
  if (bias) {
    ax += bias[2 * lane];
    ay += bias[2 * lane + 1];
  }
  if (relu) {
    ax = fmaxf(ax, 0.f);
    ay = fmaxf(ay, 0.f);
  }
  ((float2*)(out + (size_t)wave * HID))[lane] = make_float2(ax, ay);
}

// ------------- Final GEMM (fused, tiled): [mu | logstd] = agg2 @ [Wmu | Wls] + [bmu | bls] -------

__global__ __launch_bounds__(256) void k_gemm2(const float* __restrict__ A,
                                               const float* __restrict__ Wmu,
                                               const float* __restrict__ bmu,
                                               const float* __restrict__ Wls,
                                               const float* __restrict__ bls,
                                               float* __restrict__ out, int n) {
  __shared__ float at[32][132];
  __shared__ float wt[32][128];  // cols 0..63 = Wmu, 64..127 = Wls
  int t = threadIdx.x;
  int r0b = blockIdx.x * 128;
  int tr = t >> 4, tc = t & 15;
  int ra = tr * 8, ca = tc * 8;
  float acc[8][8];
#pragma unroll
  for (int i = 0; i < 8; i++)
#pragma unroll
    for (int j = 0; j < 8; j++) acc[i][j] = 0.f;

  for (int k0 = 0; k0 < HID; k0 += 32) {
    __syncthreads();
#pragma unroll
    for (int i = 0; i < 4; i++) {
      int c = t + 256 * i;
      int row = c >> 3;
      int kc = (c & 7) * 4;
      int gr = r0b + row;
      float4 v = make_float4(0.f, 0.f, 0.f, 0.f);
      if (gr < n) v = *(const float4*)(A + (size_t)gr * HID + k0 + kc);
      at[kc + 0][row] = v.x;
      at[kc + 1][row] = v.y;
      at[kc + 2][row] = v.z;
      at[kc + 3][row] = v.w;
    }
#pragma unroll
    for (int i = 0; i < 4; i++) {
      int c = t + 256 * i;
      int kr = c >> 5;
      int kc = (c & 31) * 4;
      const float* Wsel = (kc < 64) ? (Wmu + (size_t)(k0 + kr) * DOUT + kc)
                                    : (Wls + (size_t)(k0 + kr) * DOUT + (kc - 64));
      *(float4*)&wt[kr][kc] = *(const float4*)Wsel;
    }
    __syncthreads();
#pragma unroll
    for (int k = 0; k < 32; k++) {
      float a[8], w[8];
      *(float4*)&a[0] = *(float4*)&at[k][ra];
      *(float4*)&a[4] = *(float4*)&at[k][ra + 4];
      *(float4*)&w[0] = *(float4*)&wt[k][ca];
      *(float4*)&w[4] = *(float4*)&wt[k][ca + 4];
#pragma unroll
      for (int i = 0; i < 8; i++)
#pragma unroll
        for (int j = 0; j < 8; j++) acc[i][j] += a[i] * w[j];
    }
  }
  // cols 0..63 -> mu (+bmu), 64..127 -> logstd (+bls); each thread's 8 cols stay in one half
  const float* bsel = (ca < 64) ? (bmu + ca) : (bls + (ca - 64));
  float b[8];
#pragma unroll
  for (int j = 0; j < 8; j++) b[j] = bsel[j];
  size_t obase = (ca < 64) ? 0 : (size_t)n * DOUT;
  int cw = (ca < 64) ? ca : (ca - 64);
#pragma unroll
  for (int i = 0; i < 8; i++) {
    int gr = r0b + ra + i;
    if (gr < n) {
      float* p = out + obase + (size_t)gr * DOUT + cw;
      *(float4*)p = make_float4(acc[i][0] + b[0], acc[i][1] + b[1], acc[i][2] + b[2],
                                acc[i][3] + b[3]);
      *(float4*)(p + 4) = make_float4(acc[i][4] + b[4], acc[i][5] + b[5], acc[i][6] + b[6],
                                      acc[i][7] + b[7]);
    }
  }
}

// ---------------- launcher ----------------

extern "C" void kernel_launch(void* const* d_in, const int* in_sizes, int n_in,
                              void* d_out, int out_size, void* d_ws, size_t ws_size,
                              hipStream_t stream) {
  const float* x   = (const float*)d_in[0];
  const int*   ei  = (const int*)d_in[1];
  const float* W1  = (const float*)d_in[2];
  const float* b1  = (const float*)d_in[3];
  const float* Wmu = (const float*)d_in[4];
  const float* bmu = (const float*)d_in[5];
  const float* Wls = (const float*)d_in[6];
  const float* bls = (const float*)d_in[7];
  float* out = (float*)d_out;

  const int N = in_sizes[0] / DIN;
  const int E = in_sizes[1] / 2;
  const int* esrc = ei;
  const int* edst = ei + E;

  char* ws = (char*)d_ws;
  size_t off = 0;
  auto alloc = [&](size_t bytes) -> void* {
    void* p = ws + off;
    off = (off + bytes + 255) & ~(size_t)255;
    return p;
  };
  float* xW    = (float*)alloc((size_t)N * HID * sizeof(float));  // reused as agg2
  float* h     = (float*)alloc((size_t)N * HID * sizeof(float));
  int* count   = (int*)alloc((size_t)N * 4);
  int* row_ptr = (int*)alloc((size_t)(N + 1) * 4);
  int* cursor  = (int*)alloc((size_t)N * 4);
  int* csr_src = (int*)alloc((size_t)E * 4);
  float* csr_w = (float*)alloc((size_t)E * 4);
  float* dinv  = (float*)alloc((size_t)N * 4);
  const int nb = ceil_div(N, SCAN_B);
  int* bsum    = (int*)alloc((size_t)(nb + 1) * 4);
  int* bdummy  = (int*)alloc(64);
  (void)ws_size; (void)n_in; (void)out_size;

  // CSR build
  hipMemsetAsync(count, 0, (size_t)N * 4, stream);
  k_hist<<<ceil_div(E, 256), 256, 0, stream>>>(edst, E, count);
  k_scan1<<<nb, SCAN_B, 0, stream>>>(count, N, row_ptr + 1, bsum);
  k_scan1<<<1, SCAN_B, 0, stream>>>(bsum, nb, bsum, bdummy);  // in-place scan of block sums
  k_scan3<<<ceil_div(N, 256), 256, 0, stream>>>(count, N, bsum, row_ptr, cursor, dinv);
  k_scatter<<<ceil_div(E, 256), 256, 0, stream>>>(esrc, edst, E, dinv, cursor, csr_src, csr_w);

  // Layer 1: h = relu(Ahat @ (x@W1) + b1)
  k_gemm1<<<ceil_div(N, 128), 256, 0, stream>>>(x, W1, xW, N);
  k_agg<<<ceil_div(N, 4), 256, 0, stream>>>(xW, row_ptr, csr_src, csr_w, dinv, b1, h, N, 1);

  // Layer 2+3: agg2 = Ahat @ h (once), then mu/logstd = agg2 @ W + b
  k_agg<<<ceil_div(N, 4), 256, 0, stream>>>(h, row_ptr, csr_src, csr_w, dinv, nullptr, xW, N, 0);
  k_gemm2<<<ceil_div(N, 128), 256, 0, stream>>>(xW, Wmu, bmu, Wls, bls, out, N);
}

// Round 3
// 508.616 us; speedup vs baseline: 1.6734x; 1.1127x over previous
//
#include <hip/hip_runtime.h>

#define DIN 128
#define HID 128
#define DOUT 64
#define SCAN_B 1024

typedef unsigned short ushort_t;
typedef unsigned int uint_t;

static inline int ceil_div(int a, int b) { return (a + b - 1) / b; }

__device__ inline ushort_t f2bf(float f) {  // round-to-nearest-even
  uint_t u = __float_as_uint(f);
  u += 0x7fff + ((u >> 16) & 1);
  return (ushort_t)(u >> 16);
}
__device__ inline uint_t pack2bf(float a, float b) {
  return (uint_t)f2bf(a) | ((uint_t)f2bf(b) << 16);
}
__device__ inline float2 bf2x2(uint_t u) {  // unpack 2 bf16 -> 2 f32 (exact)
  return make_float2(__uint_as_float(u << 16), __uint_as_float(u & 0xffff0000u));
}

// ---------------- CSR build ----------------

__global__ void k_hist(const int* __restrict__ dst, int E, int* __restrict__ count) {
  int i = blockIdx.x * blockDim.x + threadIdx.x;
  if (i < E) atomicAdd(&count[dst[i]], 1);
}

// Inclusive scan of `in[0..n)` -> incl[0..n); per-block totals -> bsum[block].
__global__ __launch_bounds__(SCAN_B) void k_scan1(const int* __restrict__ in, int n,
                                                  int* __restrict__ incl,
                                                  int* __restrict__ bsum) {
  __shared__ int ws[SCAN_B / 64];
  int t = threadIdx.x;
  int i = blockIdx.x * SCAN_B + t;
  int lane = t & 63, w = t >> 6;
  int v = (i < n) ? in[i] : 0;
#pragma unroll
  for (int d = 1; d < 64; d <<= 1) {
    int u = __shfl_up(v, d, 64);
    if (lane >= d) v += u;
  }
  if (lane == 63) ws[w] = v;
  __syncthreads();
  if (w == 0) {
    int s = (lane < SCAN_B / 64) ? ws[lane] : 0;
#pragma unroll
    for (int d = 1; d < SCAN_B / 64; d <<= 1) {
      int u = __shfl_up(s, d, 64);
      if (lane >= d) s += u;
    }
    if (lane < SCAN_B / 64) ws[lane] = s;
  }
  __syncthreads();
  if (w > 0) v += ws[w - 1];
  if (i < n) incl[i] = v;
  if (t == SCAN_B - 1) bsum[blockIdx.x] = v;
}

// Finalize: row_ptr[i+1] = incl + block offset; cursor[i] = row_ptr[i]; dinv.
__global__ void k_scan3(const int* __restrict__ count, int n,
                        const int* __restrict__ bsum_incl,
                        int* __restrict__ row_ptr,  // incl partials already at row_ptr+1
                        int* __restrict__ cursor, float* __restrict__ dinv) {
  int i = blockIdx.x * blockDim.x + threadIdx.x;
  if (i < n) {
    int b = i >> 10;
    int v = row_ptr[i + 1] + (b > 0 ? bsum_incl[b - 1] : 0);
    row_ptr[i + 1] = v;
    int c = count[i];
    cursor[i] = v - c;
    dinv[i] = rsqrtf((float)c + 1.0f);  // +1 = self-loop
    if (i == 0) row_ptr[0] = 0;
  }
}

__global__ void k_scatter(const int* __restrict__ src, const int* __restrict__ dst, int E,
                          const float* __restrict__ dinv, int* __restrict__ cursor,
                          int2* __restrict__ csr) {
  int i = blockIdx.x * blockDim.x + threadIdx.x;
  if (i < E) {
    int s = src[i];
    int d = dst[i];
    int p = atomicAdd(&cursor[d], 1);
    csr[p] = make_int2(s, __float_as_int(dinv[s]));
  }
}

// ---------------- GEMM 1: xW = x @ W1  (N x 128)@(128 x 128), bf16 output ----------------
// 128x128 tile / 256 threads; 8x8 micro-tile; A & W staged in LDS.

__global__ __launch_bounds__(256) void k_gemm1(const float* __restrict__ A,
                                               const float* __restrict__ W,
                                               ushort_t* __restrict__ C, int n) {
  __shared__ float at[32][132];  // k-major transposed A tile
  __shared__ float wt[32][128];  // k-major W tile
  int t = threadIdx.x;
  int r0b = blockIdx.x * 128;
  int tr = t >> 4, tc = t & 15;
  int ra = tr * 8, ca = tc * 8;
  float acc[8][8];
#pragma unroll
  for (int i = 0; i < 8; i++)
#pragma unroll
    for (int j = 0; j < 8; j++) acc[i][j] = 0.f;

  for (int k0 = 0; k0 < DIN; k0 += 32) {
    __syncthreads();
#pragma unroll
    for (int i = 0; i < 4; i++) {
      int c = t + 256 * i;
      int row = c >> 3;
      int kc = (c & 7) * 4;
      int gr = r0b + row;
      float4 v = make_float4(0.f, 0.f, 0.f, 0.f);
      if (gr < n) v = *(const float4*)(A + (size_t)gr * DIN + k0 + kc);
      at[kc + 0][row] = v.x;
      at[kc + 1][row] = v.y;
      at[kc + 2][row] = v.z;
      at[kc + 3][row] = v.w;
    }
#pragma unroll
    for (int i = 0; i < 4; i++) {
      int c = t + 256 * i;
      int kr = c >> 5;
      int kc = (c & 31) * 4;
      *(float4*)&wt[kr][kc] = *(const float4*)(W + (size_t)(k0 + kr) * HID + kc);
    }
    __syncthreads();
#pragma unroll
    for (int k = 0; k < 32; k++) {
      float a[8], w[8];
      *(float4*)&a[0] = *(float4*)&at[k][ra];
      *(float4*)&a[4] = *(float4*)&at[k][ra + 4];
      *(float4*)&w[0] = *(float4*)&wt[k][ca];
      *(float4*)&w[4] = *(float4*)&wt[k][ca + 4];
#pragma unroll
      for (int i = 0; i < 8; i++)
#pragma unroll
        for (int j = 0; j < 8; j++) acc[i][j] += a[i] * w[j];
    }
  }
#pragma unroll
  for (int i = 0; i < 8; i++) {
    int gr = r0b + ra + i;
    if (gr < n) {
      uint4 v;
      v.x = pack2bf(acc[i][0], acc[i][1]);
      v.y = pack2bf(acc[i][2], acc[i][3]);
      v.z = pack2bf(acc[i][4], acc[i][5]);
      v.w = pack2bf(acc[i][6], acc[i][7]);
      *(uint4*)(C + (size_t)gr * HID + ca) = v;
    }
  }
}

// ------------- Aggregation over bf16 H:
// out[n] = sum_{e: dst=n} dinv[n]*dinv[src]*H[src] + dinv[n]^2*H[n]  (+bias,relu)
// one wave per node, lane owns a bf16x2 column pair -------------

__global__ __launch_bounds__(256) void k_agg(const ushort_t* __restrict__ H,
                                             const int* __restrict__ row_ptr,
                                             const int2* __restrict__ csr,
                                             const float* __restrict__ dinv,
                                             const float* __restrict__ bias,
                                             void* __restrict__ out, int n, int obf16) {
  int node = (blockIdx.x * blockDim.x + threadIdx.x) >> 6;
  int lane = threadIdx.x & 63;
  if (node >= n) return;
  float dn = dinv[node];
  int beg = row_ptr[node], end = row_ptr[node + 1];
  uint_t hv = *(const uint_t*)(H + (size_t)node * HID + 2 * lane);
  float2 hs = bf2x2(hv);
  float wself = dn * dn;
  float ax = wself * hs.x, ay = wself * hs.y;
  int j = beg;
  for (; j + 1 < end; j += 2) {
    int2 e0 = csr[j], e1 = csr[j + 1];
    float w0 = dn * __int_as_float(e0.y);
    float w1 = dn * __int_as_float(e1.y);
    uint_t v0 = *(const uint_t*)(H + (size_t)e0.x * HID + 2 * lane);
    uint_t v1 = *(const uint_t*)(H + (size_t)e1.x * HID + 2 * lane);
    float2 f0 = bf2x2(v0), f1 = bf2x2(v1);
    ax += w0 * f0.x;
    ay += w0 * f0.y;
    ax += w1 * f1.x;
    ay += w1 * f1.y;
  }
  if (j < end) {
    int2 e = csr[j];
    float w = dn * __int_as_float(e.y);
    uint_t v = *(const uint_t*)(H + (size_t)e.x * HID + 2 * lane);
    float2 f = bf2x2(v);
    ax += w * f.x;
    ay += w * f.y;
  }
  if (bias) {
    ax += bias[2 * lane];
    ay += bias[2 * lane + 1];
  }
  if (obf16) {  // bias+relu path writes bf16 rows for the next gather
    ax = fmaxf(ax, 0.f);
    ay = fmaxf(ay, 0.f);
    ((uint_t*)out)[(size_t)node * 64 + lane] = pack2bf(ax, ay);
  } else {
    ((float2*)out)[(size_t)node * 64 + lane] = make_float2(ax, ay);
  }
}

// ------------- Final GEMM (fused, tiled): [mu | logstd] = agg2 @ [Wmu | Wls] + [bmu | bls] -------

__global__ __launch_bounds__(256) void k_gemm2(const float* __restrict__ A,
                                               const float* __restrict__ Wmu,
                                               const float* __restrict__ bmu,
                                               const float* __restrict__ Wls,
                                               const float* __restrict__ bls,
                                               float* __restrict__ out, int n) {
  __shared__ float at[32][132];
  __shared__ float wt[32][128];  // cols 0..63 = Wmu, 64..127 = Wls
  int t = threadIdx.x;
  int r0b = blockIdx.x * 128;
  int tr = t >> 4, tc = t & 15;
  int ra = tr * 8, ca = tc * 8;
  float acc[8][8];
#pragma unroll
  for (int i = 0; i < 8; i++)
#pragma unroll
    for (int j = 0; j < 8; j++) acc[i][j] = 0.f;

  for (int k0 = 0; k0 < HID; k0 += 32) {
    __syncthreads();
#pragma unroll
    for (int i = 0; i < 4; i++) {
      int c = t + 256 * i;
      int row = c >> 3;
      int kc = (c & 7) * 4;
      int gr = r0b + row;
      float4 v = make_float4(0.f, 0.f, 0.f, 0.f);
      if (gr < n) v = *(const float4*)(A + (size_t)gr * HID + k0 + kc);
      at[kc + 0][row] = v.x;
      at[kc + 1][row] = v.y;
      at[kc + 2][row] = v.z;
      at[kc + 3][row] = v.w;
    }
#pragma unroll
    for (int i = 0; i < 4; i++) {
      int c = t + 256 * i;
      int kr = c >> 5;
      int kc = (c & 31) * 4;
      const float* Wsel = (kc < 64) ? (Wmu + (size_t)(k0 + kr) * DOUT + kc)
                                    : (Wls + (size_t)(k0 + kr) * DOUT + (kc - 64));
      *(float4*)&wt[kr][kc] = *(const float4*)Wsel;
    }
    __syncthreads();
#pragma unroll
    for (int k = 0; k < 32; k++) {
      float a[8], w[8];
      *(float4*)&a[0] = *(float4*)&at[k][ra];
      *(float4*)&a[4] = *(float4*)&at[k][ra + 4];
      *(float4*)&w[0] = *(float4*)&wt[k][ca];
      *(float4*)&w[4] = *(float4*)&wt[k][ca + 4];
#pragma unroll
      for (int i = 0; i < 8; i++)
#pragma unroll
        for (int j = 0; j < 8; j++) acc[i][j] += a[i] * w[j];
    }
  }
  const float* bsel = (ca < 64) ? (bmu + ca) : (bls + (ca - 64));
  float b[8];
#pragma unroll
  for (int j = 0; j < 8; j++) b[j] = bsel[j];
  size_t obase = (ca < 64) ? 0 : (size_t)n * DOUT;
  int cw = (ca < 64) ? ca : (ca - 64);
#pragma unroll
  for (int i = 0; i < 8; i++) {
    int gr = r0b + ra + i;
    if (gr < n) {
      float* p = out + obase + (size_t)gr * DOUT + cw;
      *(float4*)p = make_float4(acc[i][0] + b[0], acc[i][1] + b[1], acc[i][2] + b[2],
                                acc[i][3] + b[3]);
      *(float4*)(p + 4) = make_float4(acc[i][4] + b[4], acc[i][5] + b[5], acc[i][6] + b[6],
                                      acc[i][7] + b[7]);
    }
  }
}

// ---------------- launcher ----------------

extern "C" void kernel_launch(void* const* d_in, const int* in_sizes, int n_in,
                              void* d_out, int out_size, void* d_ws, size_t ws_size,
                              hipStream_t stream) {
  const float* x   = (const float*)d_in[0];
  const int*   ei  = (const int*)d_in[1];
  const float* W1  = (const float*)d_in[2];
  const float* b1  = (const float*)d_in[3];
  const float* Wmu = (const float*)d_in[4];
  const float* bmu = (const float*)d_in[5];
  const float* Wls = (const float*)d_in[6];
  const float* bls = (const float*)d_in[7];
  float* out = (float*)d_out;

  const int N = in_sizes[0] / DIN;
  const int E = in_sizes[1] / 2;
  const int* esrc = ei;
  const int* edst = ei + E;

  char* ws = (char*)d_ws;
  size_t off = 0;
  auto alloc = [&](size_t bytes) -> void* {
    void* p = ws + off;
    off = (off + bytes + 255) & ~(size_t)255;
    return p;
  };
  // xW: bf16 output of gemm1, later reused as fp32 agg2 -> alloc fp32 size.
  float* xWf     = (float*)alloc((size_t)N * HID * sizeof(float));
  ushort_t* xWb  = (ushort_t*)xWf;
  ushort_t* h    = (ushort_t*)alloc((size_t)N * HID * sizeof(ushort_t));  // bf16
  int* count   = (int*)alloc((size_t)N * 4);
  int* row_ptr = (int*)alloc((size_t)(N + 1) * 4);
  int* cursor  = (int*)alloc((size_t)N * 4);
  int2* csr    = (int2*)alloc((size_t)E * 8);
  float* dinv  = (float*)alloc((size_t)N * 4);
  const int nb = ceil_div(N, SCAN_B);
  int* bsum    = (int*)alloc((size_t)(nb + 1) * 4);
  int* bdummy  = (int*)alloc(64);
  (void)ws_size; (void)n_in; (void)out_size;

  // CSR build
  hipMemsetAsync(count, 0, (size_t)N * 4, stream);
  k_hist<<<ceil_div(E, 256), 256, 0, stream>>>(edst, E, count);
  k_scan1<<<nb, SCAN_B, 0, stream>>>(count, N, row_ptr + 1, bsum);
  k_scan1<<<1, SCAN_B, 0, stream>>>(bsum, nb, bsum, bdummy);
  k_scan3<<<ceil_div(N, 256), 256, 0, stream>>>(count, N, bsum, row_ptr, cursor, dinv);
  k_scatter<<<ceil_div(E, 256), 256, 0, stream>>>(esrc, edst, E, dinv, cursor, csr);

  // Layer 1: h = relu(Ahat @ (x@W1) + b1)   [bf16 gather operand + bf16 h]
  k_gemm1<<<ceil_div(N, 128), 256, 0, stream>>>(x, W1, xWb, N);
  k_agg<<<ceil_div(N, 4), 256, 0, stream>>>(xWb, row_ptr, csr, dinv, b1, h, N, 1);

  // Layer 2+3: agg2 = Ahat @ h (fp32 out), then mu/logstd = agg2 @ W + b
  k_agg<<<ceil_div(N, 4), 256, 0, stream>>>(h, row_ptr, csr, dinv, nullptr, xWf, N, 0);
  k_gemm2<<<ceil_div(N, 128), 256, 0, stream>>>(xWf, Wmu, bmu, Wls, bls, out, N);
}

// Round 4
// 314.677 us; speedup vs baseline: 2.7047x; 1.6163x over previous
//
#include <hip/hip_runtime.h>

#define DIN 128
#define HID 128
#define DOUT 64
#define NCHUNK 196   // edge chunks (phase A/B blocks); must be <= 256
#define BSH 9        // bucket covers 512 nodes; nb1 = ceil(N/512) must be <= 256
#define NB1MAX 256

typedef unsigned short ushort_t;
typedef unsigned int uint_t;

static inline int ceil_div(int a, int b) { return (a + b - 1) / b; }

__device__ inline ushort_t f2bf(float f) {  // round-to-nearest-even
  uint_t u = __float_as_uint(f);
  u += 0x7fff + ((u >> 16) & 1);
  return (ushort_t)(u >> 16);
}
__device__ inline uint_t pack2bf(float a, float b) {
  return (uint_t)f2bf(a) | ((uint_t)f2bf(b) << 16);
}
__device__ inline float2 bf2x2(uint_t u) {  // unpack 2 bf16 -> 2 f32 (exact)
  return make_float2(__uint_as_float(u << 16), __uint_as_float(u & 0xffff0000u));
}

// inclusive block scan over 256 threads (one value per thread)
__device__ inline int blk_scan_incl(int v, int* ws) {
  int t = threadIdx.x, lane = t & 63, w = t >> 6;
#pragma unroll
  for (int d = 1; d < 64; d <<= 1) {
    int u = __shfl_up(v, d, 64);
    if (lane >= d) v += u;
  }
  if (lane == 63) ws[w] = v;
  __syncthreads();
  if (w == 0) {
    int s = (lane < 4) ? ws[lane] : 0;
#pragma unroll
    for (int d = 1; d < 4; d <<= 1) {
      int u = __shfl_up(s, d, 64);
      if (lane >= d) s += u;
    }
    if (lane < 4) ws[lane] = s;
  }
  __syncthreads();
  if (w > 0) v += ws[w - 1];
  return v;
}

// ---------------- bucketed counting sort (CSR build) ----------------

// Phase A: per-chunk histogram of coarse buckets (dst >> BSH).
__global__ __launch_bounds__(256) void k_bhist(const int* __restrict__ dst, int E, int CH,
                                               int nb1, int* __restrict__ counts) {
  __shared__ uint_t cnt[NB1MAX];
  int t = threadIdx.x, c = blockIdx.x;
  for (int i = t; i < nb1; i += 256) cnt[i] = 0;
  __syncthreads();
  int e0 = c * CH, e1 = min(E, e0 + CH);
  for (int i = e0 + t; i < e1; i += 256) atomicAdd(&cnt[((uint_t)dst[i]) >> BSH], 1u);
  __syncthreads();
  for (int i = t; i < nb1; i += 256) counts[c * nb1 + i] = (int)cnt[i];
}

// Phase B1: per bucket, exclusive scan over chunks -> chunk_off; bucket totals.
__global__ __launch_bounds__(256) void k_bscan(const int* __restrict__ counts, int nb1,
                                               int* __restrict__ chunk_off,
                                               int* __restrict__ btot) {
  __shared__ int ws[4];
  int b = blockIdx.x, t = threadIdx.x;
  int v = (t < NCHUNK) ? counts[t * nb1 + b] : 0;
  int incl = blk_scan_incl(v, ws);
  if (t < NCHUNK) chunk_off[t * nb1 + b] = incl - v;
  if (t == NCHUNK - 1) btot[b] = incl;
}

// Phase B2: exclusive scan of bucket totals -> bucket_base.
__global__ __launch_bounds__(256) void k_bbase(const int* __restrict__ btot, int nb1, int E,
                                               int* __restrict__ bbase) {
  __shared__ int ws[4];
  int t = threadIdx.x;
  int v = (t < nb1) ? btot[t] : 0;
  int incl = blk_scan_incl(v, ws);
  if (t < nb1) bbase[t] = incl - v;
  if (t == 0) bbase[nb1] = E;
}

// Phase C: coarse scatter into bucket segments; pack (dst&511)<<17 | src (4B/edge).
__global__ __launch_bounds__(256) void k_bscatter(const int* __restrict__ src,
                                                  const int* __restrict__ dst, int E, int CH,
                                                  int nb1, const int* __restrict__ bbase,
                                                  const int* __restrict__ chunk_off,
                                                  uint_t* __restrict__ tmp) {
  __shared__ uint_t cur[NB1MAX];
  int t = threadIdx.x, c = blockIdx.x;
  for (int i = t; i < nb1; i += 256)
    cur[i] = (uint_t)(bbase[i] + chunk_off[c * nb1 + i]);
  __syncthreads();
  int e0 = c * CH, e1 = min(E, e0 + CH);
  for (int i = e0 + t; i < e1; i += 256) {
    uint_t d = (uint_t)dst[i];
    uint_t s = (uint_t)src[i];
    uint_t p = atomicAdd(&cur[d >> BSH], 1u);
    tmp[p] = ((d & ((1u << BSH) - 1)) << 17) | s;
  }
}

// Phase D: one block per bucket. LDS hist over 512 local nodes -> row_ptr/dinv,
// then scatter src into final CSR (random writes confined to one ~33KB window).
__global__ __launch_bounds__(256) void k_bfinal(const uint_t* __restrict__ tmp,
                                                const int* __restrict__ bbase, int N, int nb1,
                                                uint_t* __restrict__ csr,
                                                int* __restrict__ row_ptr,
                                                float* __restrict__ dinv) {
  __shared__ uint_t cnt[1 << BSH];
  __shared__ uint_t pfx[(1 << BSH) + 1];
  int b = blockIdx.x, t = threadIdx.x;
  int seg0 = bbase[b], seg1 = bbase[b + 1];
  for (int i = t; i < (1 << BSH); i += 256) cnt[i] = 0;
  __syncthreads();
  for (int i = seg0 + t; i < seg1; i += 256) atomicAdd(&cnt[tmp[i] >> 17], 1u);
  __syncthreads();
  if (t < 64) {  // wave 0: scan 512 counters, 8 per lane
    uint_t s = 0;
#pragma unroll
    for (int k = 0; k < 8; k++) s += cnt[t * 8 + k];
    int incl = (int)s;
#pragma unroll
    for (int d = 1; d < 64; d <<= 1) {
      int u = __shfl_up(incl, d, 64);
      if (t >= d) incl += u;
    }
    uint_t excl = (uint_t)incl - s;
#pragma unroll
    for (int k = 0; k < 8; k++) {
      pfx[t * 8 + k] = excl;
      excl += cnt[t * 8 + k];
    }
    if (t == 63) pfx[1 << BSH] = excl;
  }
  __syncthreads();
  int nd0 = b << BSH;
  for (int i = t; i < (1 << BSH); i += 256) {
    int g = nd0 + i;
    if (g < N) {
      row_ptr[g] = seg0 + (int)pfx[i];
      dinv[g] = rsqrtf((float)cnt[i] + 1.0f);  // +1 = self-loop
    }
  }
  if (b == nb1 - 1 && t == 0) row_ptr[N] = seg1;
  __syncthreads();
  for (int i = seg0 + t; i < seg1; i += 256) {
    uint_t v = tmp[i];
    uint_t pos = atomicAdd(&pfx[v >> 17], 1u);
    csr[seg0 + (int)pos] = v & 0x1FFFFu;
  }
}

// ---------------- GEMM 1: xW = x @ W1  (N x 128)@(128 x 128), bf16 output ----------------

__global__ __launch_bounds__(256) void k_gemm1(const float* __restrict__ A,
                                               const float* __restrict__ W,
                                               ushort_t* __restrict__ C, int n) {
  __shared__ float at[32][132];
  __shared__ float wt[32][128];
  int t = threadIdx.x;
  int r0b = blockIdx.x * 128;
  int tr = t >> 4, tc = t & 15;
  int ra = tr * 8, ca = tc * 8;
  float acc[8][8];
#pragma unroll
  for (int i = 0; i < 8; i++)
#pragma unroll
    for (int j = 0; j < 8; j++) acc[i][j] = 0.f;

  for (int k0 = 0; k0 < DIN; k0 += 32) {
    __syncthreads();
#pragma unroll
    for (int i = 0; i < 4; i++) {
      int c = t + 256 * i;
      int row = c >> 3;
      int kc = (c & 7) * 4;
      int gr = r0b + row;
      float4 v = make_float4(0.f, 0.f, 0.f, 0.f);
      if (gr < n) v = *(const float4*)(A + (size_t)gr * DIN + k0 + kc);
      at[kc + 0][row] = v.x;
      at[kc + 1][row] = v.y;
      at[kc + 2][row] = v.z;
      at[kc + 3][row] = v.w;
    }
#pragma unroll
    for (int i = 0; i < 4; i++) {
      int c = t + 256 * i;
      int kr = c >> 5;
      int kc = (c & 31) * 4;
      *(float4*)&wt[kr][kc] = *(const float4*)(W + (size_t)(k0 + kr) * HID + kc);
    }
    __syncthreads();
#pragma unroll
    for (int k = 0; k < 32; k++) {
      float a[8], w[8];
      *(float4*)&a[0] = *(float4*)&at[k][ra];
      *(float4*)&a[4] = *(float4*)&at[k][ra + 4];
      *(float4*)&w[0] = *(float4*)&wt[k][ca];
      *(float4*)&w[4] = *(float4*)&wt[k][ca + 4];
#pragma unroll
      for (int i = 0; i < 8; i++)
#pragma unroll
        for (int j = 0; j < 8; j++) acc[i][j] += a[i] * w[j];
    }
  }
#pragma unroll
  for (int i = 0; i < 8; i++) {
    int gr = r0b + ra + i;
    if (gr < n) {
      uint4 v;
      v.x = pack2bf(acc[i][0], acc[i][1]);
      v.y = pack2bf(acc[i][2], acc[i][3]);
      v.z = pack2bf(acc[i][4], acc[i][5]);
      v.w = pack2bf(acc[i][6], acc[i][7]);
      *(uint4*)(C + (size_t)gr * HID + ca) = v;
    }
  }
}

// ------------- Aggregation over bf16 H (one wave per node, lane owns 2 cols) -------------

__global__ __launch_bounds__(256) void k_agg(const ushort_t* __restrict__ H,
                                             const int* __restrict__ row_ptr,
                                             const uint_t* __restrict__ csr,
                                             const float* __restrict__ dinv,
                                             const float* __restrict__ bias,
                                             void* __restrict__ out, int n, int obf16) {
  int node = (blockIdx.x * blockDim.x + threadIdx.x) >> 6;
  int lane = threadIdx.x & 63;
  if (node >= n) return;
  const uint_t* Hu = (const uint_t*)H;
  float dn = dinv[node];
  int beg = row_ptr[node], end = row_ptr[node + 1];
  float2 hs = bf2x2(Hu[(size_t)node * 64 + lane]);
  float wself = dn * dn;
  float ax = wself * hs.x, ay = wself * hs.y;
  int j = beg;
  for (; j + 3 < end; j += 4) {
    uint_t s0 = csr[j], s1 = csr[j + 1], s2 = csr[j + 2], s3 = csr[j + 3];
    float w0 = dn * dinv[s0], w1 = dn * dinv[s1], w2 = dn * dinv[s2], w3 = dn * dinv[s3];
    uint_t v0 = Hu[(size_t)s0 * 64 + lane];
    uint_t v1 = Hu[(size_t)s1 * 64 + lane];
    uint_t v2 = Hu[(size_t)s2 * 64 + lane];
    uint_t v3 = Hu[(size_t)s3 * 64 + lane];
    float2 f0 = bf2x2(v0), f1 = bf2x2(v1), f2 = bf2x2(v2), f3 = bf2x2(v3);
    ax += w0 * f0.x; ay += w0 * f0.y;
    ax += w1 * f1.x; ay += w1 * f1.y;
    ax += w2 * f2.x; ay += w2 * f2.y;
    ax += w3 * f3.x; ay += w3 * f3.y;
  }
  for (; j < end; j++) {
    uint_t s = csr[j];
    float w = dn * dinv[s];
    float2 f = bf2x2(Hu[(size_t)s * 64 + lane]);
    ax += w * f.x;
    ay += w * f.y;
  }
  if (bias) {
    ax += bias[2 * lane];
    ay += bias[2 * lane + 1];
  }
  if (obf16) {
    ax = fmaxf(ax, 0.f);
    ay = fmaxf(ay, 0.f);
    ((uint_t*)out)[(size_t)node * 64 + lane] = pack2bf(ax, ay);
  } else {
    ((float2*)out)[(size_t)node * 64 + lane] = make_float2(ax, ay);
  }
}

// ------------- Final GEMM (fused, tiled): [mu | logstd] = agg2 @ [Wmu | Wls] + b -------------

__global__ __launch_bounds__(256) void k_gemm2(const float* __restrict__ A,
                                               const float* __restrict__ Wmu,
                                               const float* __restrict__ bmu,
                                               const float* __restrict__ Wls,
                                               const float* __restrict__ bls,
                                               float* __restrict__ out, int n) {
  __shared__ float at[32][132];
  __shared__ float wt[32][128];  // cols 0..63 = Wmu, 64..127 = Wls
  int t = threadIdx.x;
  int r0b = blockIdx.x * 128;
  int tr = t >> 4, tc = t & 15;
  int ra = tr * 8, ca = tc * 8;
  float acc[8][8];
#pragma unroll
  for (int i = 0; i < 8; i++)
#pragma unroll
    for (int j = 0; j < 8; j++) acc[i][j] = 0.f;

  for (int k0 = 0; k0 < HID; k0 += 32) {
    __syncthreads();
#pragma unroll
    for (int i = 0; i < 4; i++) {
      int c = t + 256 * i;
      int row = c >> 3;
      int kc = (c & 7) * 4;
      int gr = r0b + row;
      float4 v = make_float4(0.f, 0.f, 0.f, 0.f);
      if (gr < n) v = *(const float4*)(A + (size_t)gr * HID + k0 + kc);
      at[kc + 0][row] = v.x;
      at[kc + 1][row] = v.y;
      at[kc + 2][row] = v.z;
      at[kc + 3][row] = v.w;
    }
#pragma unroll
    for (int i = 0; i < 4; i++) {
      int c = t + 256 * i;
      int kr = c >> 5;
      int kc = (c & 31) * 4;
      const float* Wsel = (kc < 64) ? (Wmu + (size_t)(k0 + kr) * DOUT + kc)
                                    : (Wls + (size_t)(k0 + kr) * DOUT + (kc - 64));
      *(float4*)&wt[kr][kc] = *(const float4*)Wsel;
    }
    __syncthreads();
#pragma unroll
    for (int k = 0; k < 32; k++) {
      float a[8], w[8];
      *(float4*)&a[0] = *(float4*)&at[k][ra];
      *(float4*)&a[4] = *(float4*)&at[k][ra + 4];
      *(float4*)&w[0] = *(float4*)&wt[k][ca];
      *(float4*)&w[4] = *(float4*)&wt[k][ca + 4];
#pragma unroll
      for (int i = 0; i < 8; i++)
#pragma unroll
        for (int j = 0; j < 8; j++) acc[i][j] += a[i] * w[j];
    }
  }
  const float* bsel = (ca < 64) ? (bmu + ca) : (bls + (ca - 64));
  float b[8];
#pragma unroll
  for (int j = 0; j < 8; j++) b[j] = bsel[j];
  size_t obase = (ca < 64) ? 0 : (size_t)n * DOUT;
  int cw = (ca < 64) ? ca : (ca - 64);
#pragma unroll
  for (int i = 0; i < 8; i++) {
    int gr = r0b + ra + i;
    if (gr < n) {
      float* p = out + obase + (size_t)gr * DOUT + cw;
      *(float4*)p = make_float4(acc[i][0] + b[0], acc[i][1] + b[1], acc[i][2] + b[2],
                                acc[i][3] + b[3]);
      *(float4*)(p + 4) = make_float4(acc[i][4] + b[4], acc[i][5] + b[5], acc[i][6] + b[6],
                                      acc[i][7] + b[7]);
    }
  }
}

// ---------------- launcher ----------------

extern "C" void kernel_launch(void* const* d_in, const int* in_sizes, int n_in,
                              void* d_out, int out_size, void* d_ws, size_t ws_size,
                              hipStream_t stream) {
  const float* x   = (const float*)d_in[0];
  const int*   ei  = (const int*)d_in[1];
  const float* W1  = (const float*)d_in[2];
  const float* b1  = (const float*)d_in[3];
  const float* Wmu = (const float*)d_in[4];
  const float* bmu = (const float*)d_in[5];
  const float* Wls = (const float*)d_in[6];
  const float* bls = (const float*)d_in[7];
  float* out = (float*)d_out;

  const int N = in_sizes[0] / DIN;
  const int E = in_sizes[1] / 2;
  const int* esrc = ei;
  const int* edst = ei + E;
  const int nb1 = ceil_div(N, 1 << BSH);  // coarse buckets (<= 256)
  const int CH = ceil_div(E, NCHUNK);

  char* ws = (char*)d_ws;
  size_t off = 0;
  auto alloc = [&](size_t bytes) -> void* {
    void* p = ws + off;
    off = (off + bytes + 255) & ~(size_t)255;
    return p;
  };
  float* xWf      = (float*)alloc((size_t)N * HID * sizeof(float));  // bf16 gemm1 out, fp32 agg2
  ushort_t* xWb   = (ushort_t*)xWf;
  ushort_t* h     = (ushort_t*)alloc((size_t)N * HID * sizeof(ushort_t));
  uint_t* csr     = (uint_t*)alloc((size_t)E * 4);
  uint_t* tmp     = (uint_t*)alloc((size_t)E * 4);
  int* counts     = (int*)alloc((size_t)NCHUNK * nb1 * 4);
  int* chunk_off  = (int*)alloc((size_t)NCHUNK * nb1 * 4);
  int* btot       = (int*)alloc((size_t)nb1 * 4);
  int* bbase      = (int*)alloc((size_t)(nb1 + 1) * 4);
  int* row_ptr    = (int*)alloc((size_t)(N + 1) * 4);
  float* dinv     = (float*)alloc((size_t)N * 4);
  (void)ws_size; (void)n_in; (void)out_size;

  // CSR build via two-level bucketed counting sort (no global atomics)
  k_bhist<<<NCHUNK, 256, 0, stream>>>(edst, E, CH, nb1, counts);
  k_bscan<<<nb1, 256, 0, stream>>>(counts, nb1, chunk_off, btot);
  k_bbase<<<1, 256, 0, stream>>>(btot, nb1, E, bbase);
  k_bscatter<<<NCHUNK, 256, 0, stream>>>(esrc, edst, E, CH, nb1, bbase, chunk_off, tmp);
  k_bfinal<<<nb1, 256, 0, stream>>>(tmp, bbase, N, nb1, csr, row_ptr, dinv);

  // Layer 1: h = relu(Ahat @ (x@W1) + b1)   [bf16 gather operand + bf16 h]
  k_gemm1<<<ceil_div(N, 128), 256, 0, stream>>>(x, W1, xWb, N);
  k_agg<<<ceil_div(N, 4), 256, 0, stream>>>(xWb, row_ptr, csr, dinv, b1, h, N, 1);

  // Layer 2+3: agg2 = Ahat @ h (fp32 out), then mu/logstd = agg2 @ W + b
  k_agg<<<ceil_div(N, 4), 256, 0, stream>>>(h, row_ptr, csr, dinv, nullptr, xWf, N, 0);
  k_gemm2<<<ceil_div(N, 128), 256, 0, stream>>>(xWf, Wmu, bmu, Wls, bls, out, N);
}

// Round 5
// 311.890 us; speedup vs baseline: 2.7289x; 1.0089x over previous
//
#include <hip/hip_runtime.h>

#define DIN 128
#define HID 128
#define DOUT 64
#define NCHUNK 196   // edge chunks (phase A/B blocks); must be <= 256
#define BSH 9        // bucket covers 512 nodes; nb1 = ceil(N/512) must be <= 256
#define NB1MAX 256
#define BSLACK 1540  // per-bucket pad slack (multiple of 4, >= 3*512+4)

typedef unsigned short ushort_t;
typedef unsigned int uint_t;

static inline int ceil_div(int a, int b) { return (a + b - 1) / b; }

__device__ inline ushort_t f2bf(float f) {  // round-to-nearest-even
  uint_t u = __float_as_uint(f);
  u += 0x7fff + ((u >> 16) & 1);
  return (ushort_t)(u >> 16);
}
__device__ inline uint_t pack2bf(float a, float b) {
  return (uint_t)f2bf(a) | ((uint_t)f2bf(b) << 16);
}
__device__ inline float2 bf2x2(uint_t u) {  // unpack 2 bf16 -> 2 f32 (exact)
  return make_float2(__uint_as_float(u << 16), __uint_as_float(u & 0xffff0000u));
}

// inclusive block scan over 256 threads (one value per thread)
__device__ inline int blk_scan_incl(int v, int* ws) {
  int t = threadIdx.x, lane = t & 63, w = t >> 6;
#pragma unroll
  for (int d = 1; d < 64; d <<= 1) {
    int u = __shfl_up(v, d, 64);
    if (lane >= d) v += u;
  }
  if (lane == 63) ws[w] = v;
  __syncthreads();
  if (w == 0) {
    int s = (lane < 4) ? ws[lane] : 0;
#pragma unroll
    for (int d = 1; d < 4; d <<= 1) {
      int u = __shfl_up(s, d, 64);
      if (lane >= d) s += u;
    }
    if (lane < 4) ws[lane] = s;
  }
  __syncthreads();
  if (w > 0) v += ws[w - 1];
  return v;
}

// ---------------- bucketed counting sort (CSR build) ----------------

// Phase A: per-chunk histogram of coarse buckets (dst >> BSH).
__global__ __launch_bounds__(256) void k_bhist(const int* __restrict__ dst, int E, int CH,
                                               int nb1, int* __restrict__ counts) {
  __shared__ uint_t cnt[NB1MAX];
  int t = threadIdx.x, c = blockIdx.x;
  for (int i = t; i < nb1; i += 256) cnt[i] = 0;
  __syncthreads();
  int e0 = c * CH, e1 = min(E, e0 + CH);
  for (int i = e0 + t; i < e1; i += 256) atomicAdd(&cnt[((uint_t)dst[i]) >> BSH], 1u);
  __syncthreads();
  for (int i = t; i < nb1; i += 256) counts[c * nb1 + i] = (int)cnt[i];
}

// Phase B1: per bucket, exclusive scan over chunks -> chunk_off; bucket totals.
__global__ __launch_bounds__(256) void k_bscan(const int* __restrict__ counts, int nb1,
                                               int* __restrict__ chunk_off,
                                               int* __restrict__ btot) {
  __shared__ int ws[4];
  int b = blockIdx.x, t = threadIdx.x;
  int v = (t < NCHUNK) ? counts[t * nb1 + b] : 0;
  int incl = blk_scan_incl(v, ws);
  if (t < NCHUNK) chunk_off[t * nb1 + b] = incl - v;
  if (t == NCHUNK - 1) btot[b] = incl;
}

// Phase B2: exclusive scan of bucket totals -> bucket_base (unpadded, in tmp[]).
__global__ __launch_bounds__(256) void k_bbase(const int* __restrict__ btot, int nb1, int E,
                                               int* __restrict__ bbase) {
  __shared__ int ws[4];
  int t = threadIdx.x;
  int v = (t < nb1) ? btot[t] : 0;
  int incl = blk_scan_incl(v, ws);
  if (t < nb1) bbase[t] = incl - v;
  if (t == 0) bbase[nb1] = E;
}

// Phase C: coarse scatter into bucket segments; pack (dst&511)<<17 | src (4B/edge).
__global__ __launch_bounds__(256) void k_bscatter(const int* __restrict__ src,
                                                  const int* __restrict__ dst, int E, int CH,
                                                  int nb1, const int* __restrict__ bbase,
                                                  const int* __restrict__ chunk_off,
                                                  uint_t* __restrict__ tmp) {
  __shared__ uint_t cur[NB1MAX];
  int t = threadIdx.x, c = blockIdx.x;
  for (int i = t; i < nb1; i += 256)
    cur[i] = (uint_t)(bbase[i] + chunk_off[c * nb1 + i]);
  __syncthreads();
  int e0 = c * CH, e1 = min(E, e0 + CH);
  for (int i = e0 + t; i < e1; i += 256) {
    uint_t d = (uint_t)dst[i];
    uint_t s = (uint_t)src[i];
    uint_t p = atomicAdd(&cur[d >> BSH], 1u);
    tmp[p] = ((d & ((1u << BSH) - 1)) << 17) | s;
  }
}

// Phase D: one block per bucket. LDS hist over 512 local nodes; segments padded to
// multiples of 4 (pad entries = sentinel N, weight 0); emit row_ptr/row_end/dinv;
// scatter src into padded CSR window.
__global__ __launch_bounds__(256) void k_bfinal(const uint_t* __restrict__ tmp,
                                                const int* __restrict__ bbase, int N, int nb1,
                                                uint_t* __restrict__ csr,
                                                int* __restrict__ row_ptr,
                                                int* __restrict__ row_end,
                                                float* __restrict__ dinv) {
  __shared__ uint_t cnt[1 << BSH];
  __shared__ uint_t ppfx[1 << BSH];  // padded exclusive prefix (stable)
  __shared__ uint_t cur[1 << BSH];   // mutable cursor
  int b = blockIdx.x, t = threadIdx.x;
  int seg0 = bbase[b], seg1 = bbase[b + 1];
  int pb = ((seg0 + 3) & ~3) + BSLACK * b;  // padded, 16B-aligned bucket base
  for (int i = t; i < (1 << BSH); i += 256) cnt[i] = 0;
  __syncthreads();
  for (int i = seg0 + t; i < seg1; i += 256) atomicAdd(&cnt[tmp[i] >> 17], 1u);
  __syncthreads();
  if (t < 64) {  // wave 0: scan 512 padded counts, 8 per lane
    uint_t pc[8];
    uint_t s = 0;
#pragma unroll
    for (int k = 0; k < 8; k++) {
      pc[k] = (cnt[t * 8 + k] + 3u) & ~3u;
      s += pc[k];
    }
    int incl = (int)s;
#pragma unroll
    for (int d = 1; d < 64; d <<= 1) {
      int u = __shfl_up(incl, d, 64);
      if (t >= d) incl += u;
    }
    uint_t excl = (uint_t)incl - s;
#pragma unroll
    for (int k = 0; k < 8; k++) {
      ppfx[t * 8 + k] = excl;
      excl += pc[k];
    }
  }
  __syncthreads();
  int nd0 = b << BSH;
  for (int i = t; i < (1 << BSH); i += 256) {
    cur[i] = ppfx[i];
    int g = nd0 + i;
    if (g < N) {
      row_ptr[g] = pb + (int)ppfx[i];
      row_end[g] = pb + (int)(ppfx[i] + ((cnt[i] + 3u) & ~3u));
      dinv[g] = rsqrtf((float)cnt[i] + 1.0f);  // +1 = self-loop
    }
  }
  __syncthreads();
  for (int i = seg0 + t; i < seg1; i += 256) {
    uint_t v = tmp[i];
    uint_t pos = atomicAdd(&cur[v >> 17], 1u);
    csr[pb + (int)pos] = v & 0x1FFFFu;
  }
  __syncthreads();
  // fill pad slots with sentinel N (dinv[N]=0 -> zero weight)
  for (int i = t; i < (1 << BSH); i += 256) {
    uint_t e0 = cur[i];  // == ppfx + cnt
    uint_t e1 = ppfx[i] + ((cnt[i] + 3u) & ~3u);
    for (uint_t k = e0; k < e1; k++) csr[pb + (int)k] = (uint_t)N;
  }
}

// ---------------- GEMM 1: xW = x @ W1  (N x 128)@(128 x 128), bf16 output ----------------

__global__ __launch_bounds__(256) void k_gemm1(const float* __restrict__ A,
                                               const float* __restrict__ W,
                                               ushort_t* __restrict__ C, int n) {
  __shared__ float at[32][132];
  __shared__ float wt[32][128];
  int t = threadIdx.x;
  int r0b = blockIdx.x * 128;
  int tr = t >> 4, tc = t & 15;
  int ra = tr * 8, ca = tc * 8;
  float acc[8][8];
#pragma unroll
  for (int i = 0; i < 8; i++)
#pragma unroll
    for (int j = 0; j < 8; j++) acc[i][j] = 0.f;

  for (int k0 = 0; k0 < DIN; k0 += 32) {
    __syncthreads();
#pragma unroll
    for (int i = 0; i < 4; i++) {
      int c = t + 256 * i;
      int row = c >> 3;
      int kc = (c & 7) * 4;
      int gr = r0b + row;
      float4 v = make_float4(0.f, 0.f, 0.f, 0.f);
      if (gr < n) v = *(const float4*)(A + (size_t)gr * DIN + k0 + kc);
      at[kc + 0][row] = v.x;
      at[kc + 1][row] = v.y;
      at[kc + 2][row] = v.z;
      at[kc + 3][row] = v.w;
    }
#pragma unroll
    for (int i = 0; i < 4; i++) {
      int c = t + 256 * i;
      int kr = c >> 5;
      int kc = (c & 31) * 4;
      *(float4*)&wt[kr][kc] = *(const float4*)(W + (size_t)(k0 + kr) * HID + kc);
    }
    __syncthreads();
#pragma unroll
    for (int k = 0; k < 32; k++) {
      float a[8], w[8];
      *(float4*)&a[0] = *(float4*)&at[k][ra];
      *(float4*)&a[4] = *(float4*)&at[k][ra + 4];
      *(float4*)&w[0] = *(float4*)&wt[k][ca];
      *(float4*)&w[4] = *(float4*)&wt[k][ca + 4];
#pragma unroll
      for (int i = 0; i < 8; i++)
#pragma unroll
        for (int j = 0; j < 8; j++) acc[i][j] += a[i] * w[j];
    }
  }
#pragma unroll
  for (int i = 0; i < 8; i++) {
    int gr = r0b + ra + i;
    if (gr < n) {
      uint4 v;
      v.x = pack2bf(acc[i][0], acc[i][1]);
      v.y = pack2bf(acc[i][2], acc[i][3]);
      v.z = pack2bf(acc[i][4], acc[i][5]);
      v.w = pack2bf(acc[i][6], acc[i][7]);
      *(uint4*)(C + (size_t)gr * HID + ca) = v;
    }
  }
}

// ------------- Aggregation over bf16 H (one wave per node, lane owns 2 cols).
// Padded CSR: rows are multiples of 4 entries; uint4 csr loads; software-pipelined.

__global__ __launch_bounds__(256) void k_agg(const ushort_t* __restrict__ H,
                                             const int* __restrict__ row_ptr,
                                             const int* __restrict__ row_end,
                                             const uint_t* __restrict__ csr,
                                             const float* __restrict__ dinv,
                                             const float* __restrict__ bias,
                                             void* __restrict__ out, int n, int obf16) {
  int node = (blockIdx.x * blockDim.x + threadIdx.x) >> 6;
  int lane = threadIdx.x & 63;
  if (node >= n) return;
  const uint_t* Hu = (const uint_t*)H;
  float dn = dinv[node];
  int j = row_ptr[node], end = row_end[node];
  float2 hs = bf2x2(Hu[(size_t)node * 64 + lane]);
  float wself = dn * dn;
  float ax = wself * hs.x, ay = wself * hs.y;
  if (j < end) {
    uint4 c = *(const uint4*)(csr + j);
    while (true) {
      int jn = j + 4;
      bool more = jn < end;
      uint4 cn;
      if (more) cn = *(const uint4*)(csr + jn);
      float w0 = dn * dinv[c.x], w1 = dn * dinv[c.y];
      float w2 = dn * dinv[c.z], w3 = dn * dinv[c.w];
      uint_t v0 = Hu[(size_t)c.x * 64 + lane];
      uint_t v1 = Hu[(size_t)c.y * 64 + lane];
      uint_t v2 = Hu[(size_t)c.z * 64 + lane];
      uint_t v3 = Hu[(size_t)c.w * 64 + lane];
      float2 f0 = bf2x2(v0), f1 = bf2x2(v1), f2 = bf2x2(v2), f3 = bf2x2(v3);
      ax += w0 * f0.x; ay += w0 * f0.y;
      ax += w1 * f1.x; ay += w1 * f1.y;
      ax += w2 * f2.x; ay += w2 * f2.y;
      ax += w3 * f3.x; ay += w3 * f3.y;
      if (!more) break;
      c = cn;
      j = jn;
    }
  }
  if (bias) {
    ax += bias[2 * lane];
    ay += bias[2 * lane + 1];
  }
  if (obf16) {
    ax = fmaxf(ax, 0.f);
    ay = fmaxf(ay, 0.f);
    ((uint_t*)out)[(size_t)node * 64 + lane] = pack2bf(ax, ay);
  } else {
    ((float2*)out)[(size_t)node * 64 + lane] = make_float2(ax, ay);
  }
}

// ------------- Final GEMM (fused, tiled): [mu | logstd] = agg2 @ [Wmu | Wls] + b -------------

__global__ __launch_bounds__(256) void k_gemm2(const float* __restrict__ A,
                                               const float* __restrict__ Wmu,
                                               const float* __restrict__ bmu,
                                               const float* __restrict__ Wls,
                                               const float* __restrict__ bls,
                                               float* __restrict__ out, int n) {
  __shared__ float at[32][132];
  __shared__ float wt[32][128];  // cols 0..63 = Wmu, 64..127 = Wls
  int t = threadIdx.x;
  int r0b = blockIdx.x * 128;
  int tr = t >> 4, tc = t & 15;
  int ra = tr * 8, ca = tc * 8;
  float acc[8][8];
#pragma unroll
  for (int i = 0; i < 8; i++)
#pragma unroll
    for (int j = 0; j < 8; j++) acc[i][j] = 0.f;

  for (int k0 = 0; k0 < HID; k0 += 32) {
    __syncthreads();
#pragma unroll
    for (int i = 0; i < 4; i++) {
      int c = t + 256 * i;
      int row = c >> 3;
      int kc = (c & 7) * 4;
      int gr = r0b + row;
      float4 v = make_float4(0.f, 0.f, 0.f, 0.f);
      if (gr < n) v = *(const float4*)(A + (size_t)gr * HID + k0 + kc);
      at[kc + 0][row] = v.x;
      at[kc + 1][row] = v.y;
      at[kc + 2][row] = v.z;
      at[kc + 3][row] = v.w;
    }
#pragma unroll
    for (int i = 0; i < 4; i++) {
      int c = t + 256 * i;
      int kr = c >> 5;
      int kc = (c & 31) * 4;
      const float* Wsel = (kc < 64) ? (Wmu + (size_t)(k0 + kr) * DOUT + kc)
                                    : (Wls + (size_t)(k0 + kr) * DOUT + (kc - 64));
      *(float4*)&wt[kr][kc] = *(const float4*)Wsel;
    }
    __syncthreads();
#pragma unroll
    for (int k = 0; k < 32; k++) {
      float a[8], w[8];
      *(float4*)&a[0] = *(float4*)&at[k][ra];
      *(float4*)&a[4] = *(float4*)&at[k][ra + 4];
      *(float4*)&w[0] = *(float4*)&wt[k][ca];
      *(float4*)&w[4] = *(float4*)&wt[k][ca + 4];
#pragma unroll
      for (int i = 0; i < 8; i++)
#pragma unroll
        for (int j = 0; j < 8; j++) acc[i][j] += a[i] * w[j];
    }
  }
  const float* bsel = (ca < 64) ? (bmu + ca) : (bls + (ca - 64));
  float b[8];
#pragma unroll
  for (int j = 0; j < 8; j++) b[j] = bsel[j];
  size_t obase = (ca < 64) ? 0 : (size_t)n * DOUT;
  int cw = (ca < 64) ? ca : (ca - 64);
#pragma unroll
  for (int i = 0; i < 8; i++) {
    int gr = r0b + ra + i;
    if (gr < n) {
      float* p = out + obase + (size_t)gr * DOUT + cw;
      *(float4*)p = make_float4(acc[i][0] + b[0], acc[i][1] + b[1], acc[i][2] + b[2],
                                acc[i][3] + b[3]);
      *(float4*)(p + 4) = make_float4(acc[i][4] + b[4], acc[i][5] + b[5], acc[i][6] + b[6],
                                      acc[i][7] + b[7]);
    }
  }
}

// ---------------- launcher ----------------

extern "C" void kernel_launch(void* const* d_in, const int* in_sizes, int n_in,
                              void* d_out, int out_size, void* d_ws, size_t ws_size,
                              hipStream_t stream) {
  const float* x   = (const float*)d_in[0];
  const int*   ei  = (const int*)d_in[1];
  const float* W1  = (const float*)d_in[2];
  const float* b1  = (const float*)d_in[3];
  const float* Wmu = (const float*)d_in[4];
  const float* bmu = (const float*)d_in[5];
  const float* Wls = (const float*)d_in[6];
  const float* bls = (const float*)d_in[7];
  float* out = (float*)d_out;

  const int N = in_sizes[0] / DIN;
  const int E = in_sizes[1] / 2;
  const int* esrc = ei;
  const int* edst = ei + E;
  const int nb1 = ceil_div(N, 1 << BSH);  // coarse buckets (<= 256)
  const int CH = ceil_div(E, NCHUNK);

  char* ws = (char*)d_ws;
  size_t off = 0;
  auto alloc = [&](size_t bytes) -> void* {
    void* p = ws + off;
    off = (off + bytes + 255) & ~(size_t)255;
    return p;
  };
  float* xWf      = (float*)alloc((size_t)(N + 1) * HID * sizeof(float));  // bf16 gemm1 out / fp32 agg2
  ushort_t* xWb   = (ushort_t*)xWf;
  ushort_t* h     = (ushort_t*)alloc((size_t)(N + 1) * HID * sizeof(ushort_t));
  uint_t* csr     = (uint_t*)alloc(((size_t)E + (size_t)(BSLACK + 8) * nb1 + 16) * 4);
  uint_t* tmp     = (uint_t*)alloc((size_t)E * 4);
  int* counts     = (int*)alloc((size_t)NCHUNK * nb1 * 4);
  int* chunk_off  = (int*)alloc((size_t)NCHUNK * nb1 * 4);
  int* btot       = (int*)alloc((size_t)nb1 * 4);
  int* bbase      = (int*)alloc((size_t)(nb1 + 1) * 4);
  int* row_ptr    = (int*)alloc((size_t)N * 4);
  int* row_end    = (int*)alloc((size_t)N * 4);
  float* dinv     = (float*)alloc((size_t)(N + 1) * 4);
  (void)ws_size; (void)n_in; (void)out_size;

  // sentinel rows/weight for pad entries
  hipMemsetAsync((char*)xWb + (size_t)N * 256, 0, 256, stream);
  hipMemsetAsync((char*)h + (size_t)N * 256, 0, 256, stream);
  hipMemsetAsync(dinv + N, 0, 4, stream);

  // CSR build via two-level bucketed counting sort (no global atomics)
  k_bhist<<<NCHUNK, 256, 0, stream>>>(edst, E, CH, nb1, counts);
  k_bscan<<<nb1, 256, 0, stream>>>(counts, nb1, chunk_off, btot);
  k_bbase<<<1, 256, 0, stream>>>(btot, nb1, E, bbase);
  k_bscatter<<<NCHUNK, 256, 0, stream>>>(esrc, edst, E, CH, nb1, bbase, chunk_off, tmp);
  k_bfinal<<<nb1, 256, 0, stream>>>(tmp, bbase, N, nb1, csr, row_ptr, row_end, dinv);

  // Layer 1: h = relu(Ahat @ (x@W1) + b1)   [bf16 gather operand + bf16 h]
  k_gemm1<<<ceil_div(N, 128), 256, 0, stream>>>(x, W1, xWb, N);
  k_agg<<<ceil_div(N, 4), 256, 0, stream>>>(xWb, row_ptr, row_end, csr, dinv, b1, h, N, 1);

  // Layer 2+3: agg2 = Ahat @ h (fp32 out), then mu/logstd = agg2 @ W + b
  k_agg<<<ceil_div(N, 4), 256, 0, stream>>>(h, row_ptr, row_end, csr, dinv, nullptr, xWf, N, 0);
  k_gemm2<<<ceil_div(N, 128), 256, 0, stream>>>(xWf, Wmu, bmu, Wls, bls, out, N);
}

// Round 6
// 304.653 us; speedup vs baseline: 2.7937x; 1.0238x over previous
//
#include <hip/hip_runtime.h>

#define DIN 128
#define HID 128
#define DOUT 64
#define NCHUNK 196   // edge chunks (phase A/B blocks); must be <= 256
#define BSH 9        // bucket covers 512 nodes; nb1 = ceil(N/512) must be <= 256
#define NB1MAX 256
#define BSLACK 1540  // per-bucket pad slack (multiple of 4, >= 3*512+4)

typedef unsigned short ushort_t;
typedef unsigned int uint_t;

static inline int ceil_div(int a, int b) { return (a + b - 1) / b; }

__device__ inline ushort_t f2bf(float f) {  // round-to-nearest-even
  uint_t u = __float_as_uint(f);
  u += 0x7fff + ((u >> 16) & 1);
  return (ushort_t)(u >> 16);
}
__device__ inline uint_t pack2bf(float a, float b) {
  return (uint_t)f2bf(a) | ((uint_t)f2bf(b) << 16);
}
__device__ inline float2 bf2x2(uint_t u) {  // unpack 2 bf16 -> 2 f32 (exact)
  return make_float2(__uint_as_float(u << 16), __uint_as_float(u & 0xffff0000u));
}

// inclusive block scan over 256 threads (one value per thread)
__device__ inline int blk_scan_incl(int v, int* ws) {
  int t = threadIdx.x, lane = t & 63, w = t >> 6;
#pragma unroll
  for (int d = 1; d < 64; d <<= 1) {
    int u = __shfl_up(v, d, 64);
    if (lane >= d) v += u;
  }
  if (lane == 63) ws[w] = v;
  __syncthreads();
  if (w == 0) {
    int s = (lane < 4) ? ws[lane] : 0;
#pragma unroll
    for (int d = 1; d < 4; d <<= 1) {
      int u = __shfl_up(s, d, 64);
      if (lane >= d) s += u;
    }
    if (lane < 4) ws[lane] = s;
  }
  __syncthreads();
  if (w > 0) v += ws[w - 1];
  return v;
}

// ---------------- bucketed counting sort (CSR build) ----------------

__global__ __launch_bounds__(256) void k_bhist(const int* __restrict__ dst, int E, int CH,
                                               int nb1, int* __restrict__ counts) {
  __shared__ uint_t cnt[NB1MAX];
  int t = threadIdx.x, c = blockIdx.x;
  for (int i = t; i < nb1; i += 256) cnt[i] = 0;
  __syncthreads();
  int e0 = c * CH, e1 = min(E, e0 + CH);
  for (int i = e0 + t; i < e1; i += 256) atomicAdd(&cnt[((uint_t)dst[i]) >> BSH], 1u);
  __syncthreads();
  for (int i = t; i < nb1; i += 256) counts[c * nb1 + i] = (int)cnt[i];
}

__global__ __launch_bounds__(256) void k_bscan(const int* __restrict__ counts, int nb1,
                                               int* __restrict__ chunk_off,
                                               int* __restrict__ btot) {
  __shared__ int ws[4];
  int b = blockIdx.x, t = threadIdx.x;
  int v = (t < NCHUNK) ? counts[t * nb1 + b] : 0;
  int incl = blk_scan_incl(v, ws);
  if (t < NCHUNK) chunk_off[t * nb1 + b] = incl - v;
  if (t == NCHUNK - 1) btot[b] = incl;
}

__global__ __launch_bounds__(256) void k_bbase(const int* __restrict__ btot, int nb1, int E,
                                               int* __restrict__ bbase) {
  __shared__ int ws[4];
  int t = threadIdx.x;
  int v = (t < nb1) ? btot[t] : 0;
  int incl = blk_scan_incl(v, ws);
  if (t < nb1) bbase[t] = incl - v;
  if (t == 0) bbase[nb1] = E;
}

__global__ __launch_bounds__(256) void k_bscatter(const int* __restrict__ src,
                                                  const int* __restrict__ dst, int E, int CH,
                                                  int nb1, const int* __restrict__ bbase,
                                                  const int* __restrict__ chunk_off,
                                                  uint_t* __restrict__ tmp) {
  __shared__ uint_t cur[NB1MAX];
  int t = threadIdx.x, c = blockIdx.x;
  for (int i = t; i < nb1; i += 256)
    cur[i] = (uint_t)(bbase[i] + chunk_off[c * nb1 + i]);
  __syncthreads();
  int e0 = c * CH, e1 = min(E, e0 + CH);
  for (int i = e0 + t; i < e1; i += 256) {
    uint_t d = (uint_t)dst[i];
    uint_t s = (uint_t)src[i];
    uint_t p = atomicAdd(&cur[d >> BSH], 1u);
    tmp[p] = ((d & ((1u << BSH) - 1)) << 17) | s;
  }
}

__global__ __launch_bounds__(256) void k_bfinal(const uint_t* __restrict__ tmp,
                                                const int* __restrict__ bbase, int N, int nb1,
                                                uint_t* __restrict__ csr,
                                                int* __restrict__ row_ptr,
                                                int* __restrict__ row_end,
                                                float* __restrict__ dinv) {
  __shared__ uint_t cnt[1 << BSH];
  __shared__ uint_t ppfx[1 << BSH];
  __shared__ uint_t cur[1 << BSH];
  int b = blockIdx.x, t = threadIdx.x;
  int seg0 = bbase[b], seg1 = bbase[b + 1];
  int pb = ((seg0 + 3) & ~3) + BSLACK * b;  // padded, 16B-aligned bucket base
  for (int i = t; i < (1 << BSH); i += 256) cnt[i] = 0;
  __syncthreads();
  for (int i = seg0 + t; i < seg1; i += 256) atomicAdd(&cnt[tmp[i] >> 17], 1u);
  __syncthreads();
  if (t < 64) {
    uint_t pc[8];
    uint_t s = 0;
#pragma unroll
    for (int k = 0; k < 8; k++) {
      pc[k] = (cnt[t * 8 + k] + 3u) & ~3u;
      s += pc[k];
    }
    int incl = (int)s;
#pragma unroll
    for (int d = 1; d < 64; d <<= 1) {
      int u = __shfl_up(incl, d, 64);
      if (t >= d) incl += u;
    }
    uint_t excl = (uint_t)incl - s;
#pragma unroll
    for (int k = 0; k < 8; k++) {
      ppfx[t * 8 + k] = excl;
      excl += pc[k];
    }
  }
  __syncthreads();
  int nd0 = b << BSH;
  for (int i = t; i < (1 << BSH); i += 256) {
    cur[i] = ppfx[i];
    int g = nd0 + i;
    if (g < N) {
      row_ptr[g] = pb + (int)ppfx[i];
      row_end[g] = pb + (int)(ppfx[i] + ((cnt[i] + 3u) & ~3u));
      dinv[g] = rsqrtf((float)cnt[i] + 1.0f);  // +1 = self-loop
    }
  }
  __syncthreads();
  for (int i = seg0 + t; i < seg1; i += 256) {
    uint_t v = tmp[i];
    uint_t pos = atomicAdd(&cur[v >> 17], 1u);
    csr[pb + (int)pos] = v & 0x1FFFFu;
  }
  __syncthreads();
  for (int i = t; i < (1 << BSH); i += 256) {
    uint_t e0 = cur[i];
    uint_t e1 = ppfx[i] + ((cnt[i] + 3u) & ~3u);
    for (uint_t k = e0; k < e1; k++) csr[pb + (int)k] = (uint_t)N;
  }
}

// ---------------- GEMM 1: xW = x @ W1, bf16 out. 64x128 tile, 4x(4+4) micro ----------------

__global__ __launch_bounds__(256) void k_gemm1(const float* __restrict__ A,
                                               const float* __restrict__ W,
                                               ushort_t* __restrict__ C, int n) {
  __shared__ float at[32][132];  // k-major transposed A tile (64 rows), 16B-aligned rows
  __shared__ float wt[32][128];
  int t = threadIdx.x;
  int r0b = blockIdx.x * 64;
  int tr = t >> 4, tc = t & 15;
  int ra = tr * 4, ca = tc * 4;  // col groups: [ca, ca+3] and [64+ca, 64+ca+3]
  float acc0[4][4], acc1[4][4];
#pragma unroll
  for (int i = 0; i < 4; i++)
#pragma unroll
    for (int j = 0; j < 4; j++) { acc0[i][j] = 0.f; acc1[i][j] = 0.f; }

  for (int k0 = 0; k0 < DIN; k0 += 32) {
    __syncthreads();
#pragma unroll
    for (int i = 0; i < 2; i++) {  // A: 64 rows x 32 k = 512 float4
      int f = t + 256 * i;
      int row = f >> 3;
      int kc = (f & 7) * 4;
      int gr = r0b + row;
      float4 v = make_float4(0.f, 0.f, 0.f, 0.f);
      if (gr < n) v = *(const float4*)(A + (size_t)gr * DIN + k0 + kc);
      at[kc + 0][row] = v.x;
      at[kc + 1][row] = v.y;
      at[kc + 2][row] = v.z;
      at[kc + 3][row] = v.w;
    }
#pragma unroll
    for (int i = 0; i < 4; i++) {  // W: 32 k x 128
      int f = t + 256 * i;
      int kr = f >> 5;
      int kc = (f & 31) * 4;
      *(float4*)&wt[kr][kc] = *(const float4*)(W + (size_t)(k0 + kr) * HID + kc);
    }
    __syncthreads();
#pragma unroll
    for (int k = 0; k < 32; k++) {
      float4 a = *(float4*)&at[k][ra];
      float4 w0 = *(float4*)&wt[k][ca];
      float4 w1 = *(float4*)&wt[k][64 + ca];
      float av[4] = {a.x, a.y, a.z, a.w};
      float w0v[4] = {w0.x, w0.y, w0.z, w0.w};
      float w1v[4] = {w1.x, w1.y, w1.z, w1.w};
#pragma unroll
      for (int i = 0; i < 4; i++)
#pragma unroll
        for (int j = 0; j < 4; j++) {
          acc0[i][j] += av[i] * w0v[j];
          acc1[i][j] += av[i] * w1v[j];
        }
    }
  }
#pragma unroll
  for (int i = 0; i < 4; i++) {
    int gr = r0b + ra + i;
    if (gr < n) {
      uint2 v0, v1;
      v0.x = pack2bf(acc0[i][0], acc0[i][1]);
      v0.y = pack2bf(acc0[i][2], acc0[i][3]);
      v1.x = pack2bf(acc1[i][0], acc1[i][1]);
      v1.y = pack2bf(acc1[i][2], acc1[i][3]);
      *(uint2*)(C + (size_t)gr * HID + ca) = v0;
      *(uint2*)(C + (size_t)gr * HID + 64 + ca) = v1;
    }
  }
}

// ------------- Aggregation over bf16 H (one wave per node, lane owns 2 cols).
// Padded CSR (rows multiple of 4); uint4 csr loads; 32-bit saddr offsets; pipelined.

__global__ __launch_bounds__(256) void k_agg(const ushort_t* __restrict__ H,
                                             const int* __restrict__ row_ptr,
                                             const int* __restrict__ row_end,
                                             const uint_t* __restrict__ csr,
                                             const float* __restrict__ dinv,
                                             const float* __restrict__ bias,
                                             void* __restrict__ out, int n, int obf16) {
  int node = (blockIdx.x * blockDim.x + threadIdx.x) >> 6;
  int lane = threadIdx.x & 63;
  if (node >= n) return;
  const char* Hb = (const char*)H;
  const char* Db = (const char*)dinv;
  uint_t loff = (uint_t)lane << 2;
  float dn = dinv[node];
  int j = row_ptr[node], end = row_end[node];
  float2 hs = bf2x2(*(const uint_t*)(Hb + ((size_t)(((uint_t)node << 8) | loff))));
  // accumulate sum(dinv_s * H[s]) with self term dn*H[node]; multiply by dn at end
  float ax = dn * hs.x, ay = dn * hs.y;
  if (j < end) {
    uint4 c = *(const uint4*)(csr + j);
    while (true) {
      int jn = j + 4;
      bool more = jn < end;
      uint4 cn;
      if (more) cn = *(const uint4*)(csr + jn);
      float w0 = *(const float*)(Db + (size_t)(c.x << 2));
      float w1 = *(const float*)(Db + (size_t)(c.y << 2));
      float w2 = *(const float*)(Db + (size_t)(c.z << 2));
      float w3 = *(const float*)(Db + (size_t)(c.w << 2));
      uint_t v0 = *(const uint_t*)(Hb + (size_t)((c.x << 8) | loff));
      uint_t v1 = *(const uint_t*)(Hb + (size_t)((c.y << 8) | loff));
      uint_t v2 = *(const uint_t*)(Hb + (size_t)((c.z << 8) | loff));
      uint_t v3 = *(const uint_t*)(Hb + (size_t)((c.w << 8) | loff));
      float2 f0 = bf2x2(v0), f1 = bf2x2(v1), f2 = bf2x2(v2), f3 = bf2x2(v3);
      ax += w0 * f0.x; ay += w0 * f0.y;
      ax += w1 * f1.x; ay += w1 * f1.y;
      ax += w2 * f2.x; ay += w2 * f2.y;
      ax += w3 * f3.x; ay += w3 * f3.y;
      if (!more) break;
      c = cn;
      j = jn;
    }
  }
  ax *= dn;
  ay *= dn;
  if (bias) {
    ax += bias[2 * lane];
    ay += bias[2 * lane + 1];
  }
  if (obf16) {
    ax = fmaxf(ax, 0.f);
    ay = fmaxf(ay, 0.f);
    ((uint_t*)out)[(size_t)node * 64 + lane] = pack2bf(ax, ay);
  } else {
    ((float2*)out)[(size_t)node * 64 + lane] = make_float2(ax, ay);
  }
}

// ------------- Final GEMM (fused): [mu | logstd] = agg2 @ [Wmu | Wls] + b. 64x128 tile ----

__global__ __launch_bounds__(256) void k_gemm2(const float* __restrict__ A,
                                               const float* __restrict__ Wmu,
                                               const float* __restrict__ bmu,
                                               const float* __restrict__ Wls,
                                               const float* __restrict__ bls,
                                               float* __restrict__ out, int n) {
  __shared__ float at[32][132];
  __shared__ float wt[32][128];  // cols 0..63 = Wmu, 64..127 = Wls
  int t = threadIdx.x;
  int r0b = blockIdx.x * 64;
  int tr = t >> 4, tc = t & 15;
  int ra = tr * 4, ca = tc * 4;  // group1 -> mu cols ca..ca+3; group2 -> ls cols ca..ca+3
  float acc0[4][4], acc1[4][4];
#pragma unroll
  for (int i = 0; i < 4; i++)
#pragma unroll
    for (int j = 0; j < 4; j++) { acc0[i][j] = 0.f; acc1[i][j] = 0.f; }

  for (int k0 = 0; k0 < HID; k0 += 32) {
    __syncthreads();
#pragma unroll
    for (int i = 0; i < 2; i++) {
      int f = t + 256 * i;
      int row = f >> 3;
      int kc = (f & 7) * 4;
      int gr = r0b + row;
      float4 v = make_float4(0.f, 0.f, 0.f, 0.f);
      if (gr < n) v = *(const float4*)(A + (size_t)gr * HID + k0 + kc);
      at[kc + 0][row] = v.x;
      at[kc + 1][row] = v.y;
      at[kc + 2][row] = v.z;
      at[kc + 3][row] = v.w;
    }
#pragma unroll
    for (int i = 0; i < 4; i++) {
      int f = t + 256 * i;
      int kr = f >> 5;
      int kc = (f & 31) * 4;
      const float* Wsel = (kc < 64) ? (Wmu + (size_t)(k0 + kr) * DOUT + kc)
                                    : (Wls + (size_t)(k0 + kr) * DOUT + (kc - 64));
      *(float4*)&wt[kr][kc] = *(const float4*)Wsel;
    }
    __syncthreads();
#pragma unroll
    for (int k = 0; k < 32; k++) {
      float4 a = *(float4*)&at[k][ra];
      float4 w0 = *(float4*)&wt[k][ca];
      float4 w1 = *(float4*)&wt[k][64 + ca];
      float av[4] = {a.x, a.y, a.z, a.w};
      float w0v[4] = {w0.x, w0.y, w0.z, w0.w};
      float w1v[4] = {w1.x, w1.y, w1.z, w1.w};
#pragma unroll
      for (int i = 0; i < 4; i++)
#pragma unroll
        for (int j = 0; j < 4; j++) {
          acc0[i][j] += av[i] * w0v[j];
          acc1[i][j] += av[i] * w1v[j];
        }
    }
  }
  float b0[4], b1[4];
#pragma unroll
  for (int j = 0; j < 4; j++) {
    b0[j] = bmu[ca + j];
    b1[j] = bls[ca + j];
  }
#pragma unroll
  for (int i = 0; i < 4; i++) {
    int gr = r0b + ra + i;
    if (gr < n) {
      *(float4*)(out + (size_t)gr * DOUT + ca) =
          make_float4(acc0[i][0] + b0[0], acc0[i][1] + b0[1], acc0[i][2] + b0[2],
                      acc0[i][3] + b0[3]);
      *(float4*)(out + (size_t)n * DOUT + (size_t)gr * DOUT + ca) =
          make_float4(acc1[i][0] + b1[0], acc1[i][1] + b1[1], acc1[i][2] + b1[2],
                      acc1[i][3] + b1[3]);
    }
  }
}

// ---------------- launcher ----------------

extern "C" void kernel_launch(void* const* d_in, const int* in_sizes, int n_in,
                              void* d_out, int out_size, void* d_ws, size_t ws_size,
                              hipStream_t stream) {
  const float* x   = (const float*)d_in[0];
  const int*   ei  = (const int*)d_in[1];
  const float* W1  = (const float*)d_in[2];
  const float* b1  = (const float*)d_in[3];
  const float* Wmu = (const float*)d_in[4];
  const float* bmu = (const float*)d_in[5];
  const float* Wls = (const float*)d_in[6];
  const float* bls = (const float*)d_in[7];
  float* out = (float*)d_out;

  const int N = in_sizes[0] / DIN;
  const int E = in_sizes[1] / 2;
  const int* esrc = ei;
  const int* edst = ei + E;
  const int nb1 = ceil_div(N, 1 << BSH);
  const int CH = ceil_div(E, NCHUNK);

  char* ws = (char*)d_ws;
  size_t off = 0;
  auto alloc = [&](size_t bytes) -> void* {
    void* p = ws + off;
    off = (off + bytes + 255) & ~(size_t)255;
    return p;
  };
  float* xWf      = (float*)alloc((size_t)(N + 1) * HID * sizeof(float));  // bf16 gemm1 out / fp32 agg2
  ushort_t* xWb   = (ushort_t*)xWf;
  ushort_t* h     = (ushort_t*)alloc((size_t)(N + 1) * HID * sizeof(ushort_t));
  uint_t* csr     = (uint_t*)alloc(((size_t)E + (size_t)(BSLACK + 8) * nb1 + 16) * 4);
  uint_t* tmp     = (uint_t*)alloc((size_t)E * 4);
  int* counts     = (int*)alloc((size_t)NCHUNK * nb1 * 4);
  int* chunk_off  = (int*)alloc((size_t)NCHUNK * nb1 * 4);
  int* btot       = (int*)alloc((size_t)nb1 * 4);
  int* bbase      = (int*)alloc((size_t)(nb1 + 1) * 4);
  int* row_ptr    = (int*)alloc((size_t)N * 4);
  int* row_end    = (int*)alloc((size_t)N * 4);
  float* dinv     = (float*)alloc((size_t)(N + 1) * 4);
  (void)ws_size; (void)n_in; (void)out_size;

  // sentinel rows/weight for pad entries
  hipMemsetAsync((char*)xWb + (size_t)N * 256, 0, 256, stream);
  hipMemsetAsync((char*)h + (size_t)N * 256, 0, 256, stream);
  hipMemsetAsync(dinv + N, 0, 4, stream);

  // CSR build via two-level bucketed counting sort (no global atomics)
  k_bhist<<<NCHUNK, 256, 0, stream>>>(edst, E, CH, nb1, counts);
  k_bscan<<<nb1, 256, 0, stream>>>(counts, nb1, chunk_off, btot);
  k_bbase<<<1, 256, 0, stream>>>(btot, nb1, E, bbase);
  k_bscatter<<<NCHUNK, 256, 0, stream>>>(esrc, edst, E, CH, nb1, bbase, chunk_off, tmp);
  k_bfinal<<<nb1, 256, 0, stream>>>(tmp, bbase, N, nb1, csr, row_ptr, row_end, dinv);

  // Layer 1: h = relu(Ahat @ (x@W1) + b1)   [bf16 gather operand + bf16 h]
  k_gemm1<<<ceil_div(N, 64), 256, 0, stream>>>(x, W1, xWb, N);
  k_agg<<<ceil_div(N, 4), 256, 0, stream>>>(xWb, row_ptr, row_end, csr, dinv, b1, h, N, 1);

  // Layer 2+3: agg2 = Ahat @ h (fp32 out), then mu/logstd = agg2 @ W + b
  k_agg<<<ceil_div(N, 4), 256, 0, stream>>>(h, row_ptr, row_end, csr, dinv, nullptr, xWf, N, 0);
  k_gemm2<<<ceil_div(N, 64), 256, 0, stream>>>(xWf, Wmu, bmu, Wls, bls, out, N);
}

// Round 7
// 239.001 us; speedup vs baseline: 3.5611x; 1.2747x over previous
//
#include <hip/hip_runtime.h>

#define DIN 128
#define HID 128
#define DOUT 64
#define NCHUNK 196   // edge chunks (phase A/B blocks); must be <= 256
#define BSH 9        // bucket covers 512 nodes; nb1 = ceil(N/512) must be <= 256
#define NB1MAX 256
#define BSLACK 1540  // per-bucket pad slack (multiple of 4, >= 3*512+4)

typedef unsigned short ushort_t;
typedef unsigned int uint_t;
typedef __attribute__((ext_vector_type(4))) short s4v;
typedef __attribute__((ext_vector_type(4))) float f4v;

#if defined(__has_builtin)
#if __has_builtin(__builtin_amdgcn_mfma_f32_16x16x16bf16_1k)
#define MFMA16(a, b, c) __builtin_amdgcn_mfma_f32_16x16x16bf16_1k(a, b, c, 0, 0, 0)
#endif
#endif
#ifndef MFMA16
static __device__ inline f4v mfma16_asm(s4v a, s4v b, f4v c) {
  asm volatile("v_mfma_f32_16x16x16_bf16 %0, %1, %2, %0" : "+v"(c) : "v"(a), "v"(b));
  return c;
}
#define MFMA16(a, b, c) mfma16_asm(a, b, c)
#endif

static inline int ceil_div(int a, int b) { return (a + b - 1) / b; }

__device__ inline ushort_t f2bf(float f) {  // round-to-nearest-even
  uint_t u = __float_as_uint(f);
  u += 0x7fff + ((u >> 16) & 1);
  return (ushort_t)(u >> 16);
}
__device__ inline uint_t pack2bf(float a, float b) {
  return (uint_t)f2bf(a) | ((uint_t)f2bf(b) << 16);
}
__device__ inline float2 bf2x2(uint_t u) {  // unpack 2 bf16 -> 2 f32 (exact)
  return make_float2(__uint_as_float(u << 16), __uint_as_float(u & 0xffff0000u));
}

// inclusive block scan over 256 threads (one value per thread)
__device__ inline int blk_scan_incl(int v, int* ws) {
  int t = threadIdx.x, lane = t & 63, w = t >> 6;
#pragma unroll
  for (int d = 1; d < 64; d <<= 1) {
    int u = __shfl_up(v, d, 64);
    if (lane >= d) v += u;
  }
  if (lane == 63) ws[w] = v;
  __syncthreads();
  if (w == 0) {
    int s = (lane < 4) ? ws[lane] : 0;
#pragma unroll
    for (int d = 1; d < 4; d <<= 1) {
      int u = __shfl_up(s, d, 64);
      if (lane >= d) s += u;
    }
    if (lane < 4) ws[lane] = s;
  }
  __syncthreads();
  if (w > 0) v += ws[w - 1];
  return v;
}

// ---------------- bucketed counting sort (CSR build) ----------------

__global__ __launch_bounds__(256) void k_bhist(const int* __restrict__ dst, int E, int CH,
                                               int nb1, int* __restrict__ counts) {
  __shared__ uint_t cnt[NB1MAX];
  int t = threadIdx.x, c = blockIdx.x;
  for (int i = t; i < nb1; i += 256) cnt[i] = 0;
  __syncthreads();
  int e0 = c * CH, e1 = min(E, e0 + CH);
  for (int i = e0 + t; i < e1; i += 256) atomicAdd(&cnt[((uint_t)dst[i]) >> BSH], 1u);
  __syncthreads();
  for (int i = t; i < nb1; i += 256) counts[c * nb1 + i] = (int)cnt[i];
}

__global__ __launch_bounds__(256) void k_bscan(const int* __restrict__ counts, int nb1,
                                               int* __restrict__ chunk_off,
                                               int* __restrict__ btot) {
  __shared__ int ws[4];
  int b = blockIdx.x, t = threadIdx.x;
  int v = (t < NCHUNK) ? counts[t * nb1 + b] : 0;
  int incl = blk_scan_incl(v, ws);
  if (t < NCHUNK) chunk_off[t * nb1 + b] = incl - v;
  if (t == NCHUNK - 1) btot[b] = incl;
}

__global__ __launch_bounds__(256) void k_bbase(const int* __restrict__ btot, int nb1, int E,
                                               int* __restrict__ bbase) {
  __shared__ int ws[4];
  int t = threadIdx.x;
  int v = (t < nb1) ? btot[t] : 0;
  int incl = blk_scan_incl(v, ws);
  if (t < nb1) bbase[t] = incl - v;
  if (t == 0) bbase[nb1] = E;
}

__global__ __launch_bounds__(256) void k_bscatter(const int* __restrict__ src,
                                                  const int* __restrict__ dst, int E, int CH,
                                                  int nb1, const int* __restrict__ bbase,
                                                  const int* __restrict__ chunk_off,
                                                  uint_t* __restrict__ tmp) {
  __shared__ uint_t cur[NB1MAX];
  int t = threadIdx.x, c = blockIdx.x;
  for (int i = t; i < nb1; i += 256)
    cur[i] = (uint_t)(bbase[i] + chunk_off[c * nb1 + i]);
  __syncthreads();
  int e0 = c * CH, e1 = min(E, e0 + CH);
  for (int i = e0 + t; i < e1; i += 256) {
    uint_t d = (uint_t)dst[i];
    uint_t s = (uint_t)src[i];
    uint_t p = atomicAdd(&cur[d >> BSH], 1u);
    tmp[p] = ((d & ((1u << BSH) - 1)) << 17) | s;
  }
}

__global__ __launch_bounds__(256) void k_bfinal(const uint_t* __restrict__ tmp,
                                                const int* __restrict__ bbase, int N, int nb1,
                                                uint_t* __restrict__ csr,
                                                int* __restrict__ row_ptr,
                                                int* __restrict__ row_end,
                                                float* __restrict__ dinv) {
  __shared__ uint_t cnt[1 << BSH];
  __shared__ uint_t ppfx[1 << BSH];
  __shared__ uint_t cur[1 << BSH];
  int b = blockIdx.x, t = threadIdx.x;
  int seg0 = bbase[b], seg1 = bbase[b + 1];
  int pb = ((seg0 + 3) & ~3) + BSLACK * b;  // padded, 16B-aligned bucket base
  for (int i = t; i < (1 << BSH); i += 256) cnt[i] = 0;
  __syncthreads();
  for (int i = seg0 + t; i < seg1; i += 256) atomicAdd(&cnt[tmp[i] >> 17], 1u);
  __syncthreads();
  if (t < 64) {
    uint_t pc[8];
    uint_t s = 0;
#pragma unroll
    for (int k = 0; k < 8; k++) {
      pc[k] = (cnt[t * 8 + k] + 3u) & ~3u;
      s += pc[k];
    }
    int incl = (int)s;
#pragma unroll
    for (int d = 1; d < 64; d <<= 1) {
      int u = __shfl_up(incl, d, 64);
      if (t >= d) incl += u;
    }
    uint_t excl = (uint_t)incl - s;
#pragma unroll
    for (int k = 0; k < 8; k++) {
      ppfx[t * 8 + k] = excl;
      excl += pc[k];
    }
  }
  __syncthreads();
  int nd0 = b << BSH;
  for (int i = t; i < (1 << BSH); i += 256) {
    cur[i] = ppfx[i];
    int g = nd0 + i;
    if (g < N) {
      row_ptr[g] = pb + (int)ppfx[i];
      row_end[g] = pb + (int)(ppfx[i] + ((cnt[i] + 3u) & ~3u));
      dinv[g] = rsqrtf((float)cnt[i] + 1.0f);  // +1 = self-loop
    }
  }
  __syncthreads();
  for (int i = seg0 + t; i < seg1; i += 256) {
    uint_t v = tmp[i];
    uint_t pos = atomicAdd(&cur[v >> 17], 1u);
    csr[pb + (int)pos] = v & 0x1FFFFu;
  }
  __syncthreads();
  for (int i = t; i < (1 << BSH); i += 256) {
    uint_t e0 = cur[i];
    uint_t e1 = ppfx[i] + ((cnt[i] + 3u) & ~3u);
    for (uint_t k = e0; k < e1; k++) csr[pb + (int)k] = (uint_t)N;
  }
}

// --------- prep: transpose weights to bf16 col-major [col][k] ----------
// Wt1[j][k] = bf(W1[k][j]); Wt2[j][k] = bf(Wmu[k][j]) for j<64 else bf(Wls[k][j-64])

__global__ __launch_bounds__(256) void k_prep(const float* __restrict__ W1,
                                              const float* __restrict__ Wmu,
                                              const float* __restrict__ Wls,
                                              ushort_t* __restrict__ Wt1,
                                              ushort_t* __restrict__ Wt2) {
  int idx = blockIdx.x * 256 + threadIdx.x;  // grid 64 -> 16384
  int j = idx >> 7, k = idx & 127;
  Wt1[j * 128 + k] = f2bf(W1[k * 128 + j]);
  Wt2[j * 128 + k] = f2bf(j < 64 ? Wmu[k * 64 + j] : Wls[k * 64 + (j - 64)]);
}

// ---------------- GEMM 1 (MFMA): xW = bf16(x) @ bf16(W1), bf16 out ----------------
// 64 rows/block, 4 waves (16 rows each, full 128 cols). W in LDS [128][132] bf16;
// A fragments straight from global fp32 (converted in-reg). One barrier total.

__global__ __launch_bounds__(256) void k_gemm1(const float* __restrict__ A,
                                               const ushort_t* __restrict__ Wt,
                                               ushort_t* __restrict__ C, int n) {
  __shared__ ushort_t Ws[128][132];  // col-major W: Ws[j][k]; stride 264B -> conflict-free b64
  int t = threadIdx.x;
#pragma unroll
  for (int i = 0; i < 16; i++) {
    int f = t + 256 * i;  // 0..4095, 8B chunks
    int rowj = f >> 5, seg = f & 31;
    *(uint2*)&Ws[rowj][seg * 4] = *(const uint2*)(Wt + rowj * 128 + seg * 4);
  }
  __syncthreads();
  int w = t >> 6, lane = t & 63;
  int rl = lane & 15, g = lane >> 4;
  int row = blockIdx.x * 64 + w * 16 + rl;
  bool valid = row < n;
  const float* Ar = A + (size_t)row * DIN + 4 * g;
  s4v af[8];
#pragma unroll
  for (int kk = 0; kk < 8; kk++) {
    float4 v = make_float4(0.f, 0.f, 0.f, 0.f);
    if (valid) v = *(const float4*)(Ar + kk * 16);
    s4v a;
    a[0] = (short)f2bf(v.x);
    a[1] = (short)f2bf(v.y);
    a[2] = (short)f2bf(v.z);
    a[3] = (short)f2bf(v.w);
    af[kk] = a;
  }
  f4v acc[8];
#pragma unroll
  for (int ct = 0; ct < 8; ct++) acc[ct] = (f4v)0.f;
#pragma unroll
  for (int kk = 0; kk < 8; kk++) {
    int ko = kk * 16 + 4 * g;
#pragma unroll
    for (int ct = 0; ct < 8; ct++) {
      s4v b = *(s4v*)&Ws[ct * 16 + rl][ko];
      acc[ct] = MFMA16(af[kk], b, acc[ct]);
    }
  }
  int gr0 = blockIdx.x * 64 + w * 16 + 4 * g;
#pragma unroll
  for (int i = 0; i < 4; i++) {
    int gr = gr0 + i;
    if (gr < n) {
#pragma unroll
      for (int ct = 0; ct < 8; ct++)
        C[(size_t)gr * HID + ct * 16 + rl] = f2bf(acc[ct][i]);
    }
  }
}

// ------------- Aggregation over bf16 H (one wave per node, lane owns 2 cols).
// Padded CSR (rows multiple of 4); uint4 csr loads; 32-bit offsets; pipelined. bf16 out.

__global__ __launch_bounds__(256) void k_agg(const ushort_t* __restrict__ H,
                                             const int* __restrict__ row_ptr,
                                             const int* __restrict__ row_end,
                                             const uint_t* __restrict__ csr,
                                             const float* __restrict__ dinv,
                                             const float* __restrict__ bias,
                                             ushort_t* __restrict__ out, int n, int relu) {
  int node = (blockIdx.x * blockDim.x + threadIdx.x) >> 6;
  int lane = threadIdx.x & 63;
  if (node >= n) return;
  const char* Hb = (const char*)H;
  const char* Db = (const char*)dinv;
  uint_t loff = (uint_t)lane << 2;
  float dn = dinv[node];
  int j = row_ptr[node], end = row_end[node];
  float2 hs = bf2x2(*(const uint_t*)(Hb + ((size_t)(((uint_t)node << 8) | loff))));
  float ax = dn * hs.x, ay = dn * hs.y;  // self term; multiply by dn at end
  if (j < end) {
    uint4 c = *(const uint4*)(csr + j);
    while (true) {
      int jn = j + 4;
      bool more = jn < end;
      uint4 cn;
      if (more) cn = *(const uint4*)(csr + jn);
      float w0 = *(const float*)(Db + (size_t)(c.x << 2));
      float w1 = *(const float*)(Db + (size_t)(c.y << 2));
      float w2 = *(const float*)(Db + (size_t)(c.z << 2));
      float w3 = *(const float*)(Db + (size_t)(c.w << 2));
      uint_t v0 = *(const uint_t*)(Hb + (size_t)((c.x << 8) | loff));
      uint_t v1 = *(const uint_t*)(Hb + (size_t)((c.y << 8) | loff));
      uint_t v2 = *(const uint_t*)(Hb + (size_t)((c.z << 8) | loff));
      uint_t v3 = *(const uint_t*)(Hb + (size_t)((c.w << 8) | loff));
      float2 f0 = bf2x2(v0), f1 = bf2x2(v1), f2 = bf2x2(v2), f3 = bf2x2(v3);
      ax += w0 * f0.x; ay += w0 * f0.y;
      ax += w1 * f1.x; ay += w1 * f1.y;
      ax += w2 * f2.x; ay += w2 * f2.y;
      ax += w3 * f3.x; ay += w3 * f3.y;
      if (!more) break;
      c = cn;
      j = jn;
    }
  }
  ax *= dn;
  ay *= dn;
  if (bias) {
    ax += bias[2 * lane];
    ay += bias[2 * lane + 1];
  }
  if (relu) {
    ax = fmaxf(ax, 0.f);
    ay = fmaxf(ay, 0.f);
  }
  ((uint_t*)out)[(size_t)node * 64 + lane] = pack2bf(ax, ay);
}

// ------------- GEMM 2 (MFMA, fused): [mu | logstd] = agg2(bf16) @ Wt2 + b, fp32 out -------

__global__ __launch_bounds__(256) void k_gemm2(const ushort_t* __restrict__ A,
                                               const ushort_t* __restrict__ Wt,
                                               const float* __restrict__ bmu,
                                               const float* __restrict__ bls,
                                               float* __restrict__ out, int n) {
  __shared__ ushort_t Ws[128][132];
  int t = threadIdx.x;
#pragma unroll
  for (int i = 0; i < 16; i++) {
    int f = t + 256 * i;
    int rowj = f >> 5, seg = f & 31;
    *(uint2*)&Ws[rowj][seg * 4] = *(const uint2*)(Wt + rowj * 128 + seg * 4);
  }
  __syncthreads();
  int w = t >> 6, lane = t & 63;
  int rl = lane & 15, g = lane >> 4;
  int row = blockIdx.x * 64 + w * 16 + rl;
  bool valid = row < n;
  const ushort_t* Ar = A + (size_t)row * HID + 4 * g;
  s4v af[8];
#pragma unroll
  for (int kk = 0; kk < 8; kk++) {
    s4v a = (s4v)0;
    if (valid) a = *(const s4v*)(Ar + kk * 16);
    af[kk] = a;
  }
  f4v acc[8];
#pragma unroll
  for (int ct = 0; ct < 8; ct++) acc[ct] = (f4v)0.f;
#pragma unroll
  for (int kk = 0; kk < 8; kk++) {
    int ko = kk * 16 + 4 * g;
#pragma unroll
    for (int ct = 0; ct < 8; ct++) {
      s4v b = *(s4v*)&Ws[ct * 16 + rl][ko];
      acc[ct] = MFMA16(af[kk], b, acc[ct]);
    }
  }
  int gr0 = blockIdx.x * 64 + w * 16 + 4 * g;
#pragma unroll
  for (int ct = 0; ct < 8; ct++) {
    int col = ct * 16 + rl;
    float bv;
    size_t obase;
    int cc;
    if (ct < 4) {
      bv = bmu[col];
      obase = 0;
      cc = col;
    } else {
      bv = bls[col - 64];
      obase = (size_t)n * DOUT;
      cc = col - 64;
    }
#pragma unroll
    for (int i = 0; i < 4; i++) {
      int gr = gr0 + i;
      if (gr < n) out[obase + (size_t)gr * DOUT + cc] = acc[ct][i] + bv;
    }
  }
}

// ---------------- launcher ----------------

extern "C" void kernel_launch(void* const* d_in, const int* in_sizes, int n_in,
                              void* d_out, int out_size, void* d_ws, size_t ws_size,
                              hipStream_t stream) {
  const float* x   = (const float*)d_in[0];
  const int*   ei  = (const int*)d_in[1];
  const float* W1  = (const float*)d_in[2];
  const float* b1  = (const float*)d_in[3];
  const float* Wmu = (const float*)d_in[4];
  const float* bmu = (const float*)d_in[5];
  const float* Wls = (const float*)d_in[6];
  const float* bls = (const float*)d_in[7];
  float* out = (float*)d_out;

  const int N = in_sizes[0] / DIN;
  const int E = in_sizes[1] / 2;
  const int* esrc = ei;
  const int* edst = ei + E;
  const int nb1 = ceil_div(N, 1 << BSH);
  const int CH = ceil_div(E, NCHUNK);

  char* ws = (char*)d_ws;
  size_t off = 0;
  auto alloc = [&](size_t bytes) -> void* {
    void* p = ws + off;
    off = (off + bytes + 255) & ~(size_t)255;
    return p;
  };
  ushort_t* xWb   = (ushort_t*)alloc((size_t)(N + 1) * HID * sizeof(ushort_t));  // gemm1 out / agg2 out
  ushort_t* h     = (ushort_t*)alloc((size_t)(N + 1) * HID * sizeof(ushort_t));
  uint_t* csr     = (uint_t*)alloc(((size_t)E + (size_t)(BSLACK + 8) * nb1 + 16) * 4);
  uint_t* tmp     = (uint_t*)alloc((size_t)E * 4);
  int* counts     = (int*)alloc((size_t)NCHUNK * nb1 * 4);
  int* chunk_off  = (int*)alloc((size_t)NCHUNK * nb1 * 4);
  int* btot       = (int*)alloc((size_t)nb1 * 4);
  int* bbase      = (int*)alloc((size_t)(nb1 + 1) * 4);
  int* row_ptr    = (int*)alloc((size_t)N * 4);
  int* row_end    = (int*)alloc((size_t)N * 4);
  float* dinv     = (float*)alloc((size_t)(N + 1) * 4);
  ushort_t* wt1b  = (ushort_t*)alloc((size_t)HID * HID * 2);
  ushort_t* wt2b  = (ushort_t*)alloc((size_t)HID * HID * 2);
  (void)ws_size; (void)n_in; (void)out_size;

  // sentinel rows/weight for pad entries
  hipMemsetAsync((char*)xWb + (size_t)N * 256, 0, 256, stream);
  hipMemsetAsync((char*)h + (size_t)N * 256, 0, 256, stream);
  hipMemsetAsync(dinv + N, 0, 4, stream);

  // weight prep (bf16, transposed)
  k_prep<<<64, 256, 0, stream>>>(W1, Wmu, Wls, wt1b, wt2b);

  // CSR build via two-level bucketed counting sort (no global atomics)
  k_bhist<<<NCHUNK, 256, 0, stream>>>(edst, E, CH, nb1, counts);
  k_bscan<<<nb1, 256, 0, stream>>>(counts, nb1, chunk_off, btot);
  k_bbase<<<1, 256, 0, stream>>>(btot, nb1, E, bbase);
  k_bscatter<<<NCHUNK, 256, 0, stream>>>(esrc, edst, E, CH, nb1, bbase, chunk_off, tmp);
  k_bfinal<<<nb1, 256, 0, stream>>>(tmp, bbase, N, nb1, csr, row_ptr, row_end, dinv);

  // Layer 1: h = relu(Ahat @ (x@W1) + b1)
  k_gemm1<<<ceil_div(N, 64), 256, 0, stream>>>(x, wt1b, xWb, N);
  k_agg<<<ceil_div(N, 4), 256, 0, stream>>>(xWb, row_ptr, row_end, csr, dinv, b1, h, N, 1);

  // Layer 2+3: agg2 = Ahat @ h (bf16 out), then [mu|logstd] = agg2 @ [Wmu|Wls] + b
  k_agg<<<ceil_div(N, 4), 256, 0, stream>>>(h, row_ptr, row_end, csr, dinv, nullptr, xWb, N, 0);
  k_gemm2<<<ceil_div(N, 64), 256, 0, stream>>>(xWb, wt2b, bmu, bls, out, N);
}

// Round 8
// 216.465 us; speedup vs baseline: 3.9318x; 1.1041x over previous
//
#include <hip/hip_runtime.h>

#define DIN 128
#define HID 128
#define DOUT 64
#define NCHUNK 784   // edge chunks (phase A/C blocks)
#define BSH 9        // bucket covers 512 nodes; nb1 = ceil(N/512) must be <= 256
#define NB1MAX 256
#define BSLACK 1540  // per-bucket pad slack (multiple of 4, >= 3*512+4)

typedef unsigned short ushort_t;
typedef unsigned int uint_t;
typedef __attribute__((ext_vector_type(4))) short s4v;
typedef __attribute__((ext_vector_type(4))) float f4v;

#if defined(__has_builtin)
#if __has_builtin(__builtin_amdgcn_mfma_f32_16x16x16bf16_1k)
#define MFMA16(a, b, c) __builtin_amdgcn_mfma_f32_16x16x16bf16_1k(a, b, c, 0, 0, 0)
#endif
#endif
#ifndef MFMA16
static __device__ inline f4v mfma16_asm(s4v a, s4v b, f4v c) {
  asm volatile("v_mfma_f32_16x16x16_bf16 %0, %1, %2, %0" : "+v"(c) : "v"(a), "v"(b));
  return c;
}
#define MFMA16(a, b, c) mfma16_asm(a, b, c)
#endif

static inline int ceil_div(int a, int b) { return (a + b - 1) / b; }

__device__ inline ushort_t f2bf(float f) {  // round-to-nearest-even
  uint_t u = __float_as_uint(f);
  u += 0x7fff + ((u >> 16) & 1);
  return (ushort_t)(u >> 16);
}
__device__ inline uint_t pack2bf(float a, float b) {
  return (uint_t)f2bf(a) | ((uint_t)f2bf(b) << 16);
}
__device__ inline float2 bf2x2(uint_t u) {  // unpack 2 bf16 -> 2 f32 (exact)
  return make_float2(__uint_as_float(u << 16), __uint_as_float(u & 0xffff0000u));
}

// inclusive scan over blockDim = nw*64 threads (one value per thread)
__device__ inline int blk_scan_incl(int v, int* ws, int nw) {
  int t = threadIdx.x, lane = t & 63, w = t >> 6;
#pragma unroll
  for (int d = 1; d < 64; d <<= 1) {
    int u = __shfl_up(v, d, 64);
    if (lane >= d) v += u;
  }
  if (lane == 63) ws[w] = v;
  __syncthreads();
  if (w == 0) {
    int s = (lane < nw) ? ws[lane] : 0;
    for (int d = 1; d < nw; d <<= 1) {
      int u = __shfl_up(s, d, 64);
      if (lane >= d) s += u;
    }
    if (lane < nw) ws[lane] = s;
  }
  __syncthreads();
  if (w > 0) v += ws[w - 1];
  return v;
}

// ---------------- setup: per-chunk coarse histogram + weight prep + sentinels -------------

__global__ __launch_bounds__(512) void k_setup(const int* __restrict__ dst, int E, int CH,
                                               int nb1, int* __restrict__ counts,
                                               const float* __restrict__ W1,
                                               const float* __restrict__ Wmu,
                                               const float* __restrict__ Wls,
                                               ushort_t* __restrict__ Wt1,
                                               ushort_t* __restrict__ Wt2,
                                               ushort_t* __restrict__ xWb,
                                               ushort_t* __restrict__ h,
                                               float* __restrict__ dinv, int N) {
  __shared__ uint_t cnt[NB1MAX];
  int b = blockIdx.x, t = threadIdx.x;
  if (b < NCHUNK) {  // coarse hist of dst>>BSH
    for (int i = t; i < nb1; i += 512) cnt[i] = 0;
    __syncthreads();
    int e0 = b * CH, e1 = min(E, e0 + CH);
    for (int i = e0 + t; i < e1; i += 512) atomicAdd(&cnt[((uint_t)dst[i]) >> BSH], 1u);
    __syncthreads();
    for (int i = t; i < nb1; i += 512) counts[b * nb1 + i] = (int)cnt[i];
  } else if (b < NCHUNK + 32) {  // weight transpose to bf16 col-major
    int idx = (b - NCHUNK) * 512 + t;  // 0..16383
    int j = idx >> 7, k = idx & 127;
    Wt1[j * 128 + k] = f2bf(W1[k * 128 + j]);
    Wt2[j * 128 + k] = f2bf(j < 64 ? Wmu[k * 64 + j] : Wls[k * 64 + (j - 64)]);
  } else {  // sentinel rows / dinv[N]
    if (t < 64) ((uint_t*)(xWb + (size_t)N * HID))[t] = 0;
    else if (t < 128) ((uint_t*)(h + (size_t)N * HID))[t - 64] = 0;
    else if (t == 128) dinv[N] = 0.f;
  }
}

// Phase B: per bucket, exclusive scan over NCHUNK chunks -> chunk_off; bucket totals.
__global__ __launch_bounds__(256) void k_bscan(const int* __restrict__ counts, int nb1,
                                               int* __restrict__ chunk_off,
                                               int* __restrict__ btot) {
  __shared__ int ws[8];
  __shared__ int shc;
  int b = blockIdx.x, t = threadIdx.x;
  int carry = 0;
#pragma unroll
  for (int r = 0; r < NCHUNK / 256 + 1; r++) {
    int idx = r * 256 + t;
    int v = (idx < NCHUNK) ? counts[idx * nb1 + b] : 0;
    int incl = blk_scan_incl(v, ws, 4) + carry;
    if (idx < NCHUNK) chunk_off[idx * nb1 + b] = incl - v;
    if (t == 255) shc = incl;
    __syncthreads();
    carry = shc;
  }
  if (t == 0) btot[b] = carry;
}

// Phase C: coarse scatter into bucket segments; pack (dst&511)<<17 | src (4B/edge).
// Bucket bases computed in-block from btot.
__global__ __launch_bounds__(256) void k_bscatter(const int* __restrict__ src,
                                                  const int* __restrict__ dst, int E, int CH,
                                                  int nb1, const int* __restrict__ btot,
                                                  const int* __restrict__ chunk_off,
                                                  uint_t* __restrict__ tmp) {
  __shared__ int ws[8];
  __shared__ uint_t cur[NB1MAX];
  int t = threadIdx.x, c = blockIdx.x;
  {
    int v = (t < nb1) ? btot[t] : 0;
    int incl = blk_scan_incl(v, ws, 4);
    if (t < nb1) cur[t] = (uint_t)(incl - v + chunk_off[c * nb1 + t]);
  }
  __syncthreads();
  int e0 = c * CH, e1 = min(E, e0 + CH);
  for (int i = e0 + t; i < e1; i += 256) {
    uint_t d = (uint_t)dst[i];
    uint_t s = (uint_t)src[i];
    uint_t p = atomicAdd(&cur[d >> BSH], 1u);
    tmp[p] = ((d & ((1u << BSH) - 1)) << 17) | s;
  }
}

// Phase D: one 512-thread block per bucket. LDS hist over 512 local nodes; segments
// padded to multiples of 4 (pad = sentinel N); emit row_ptr/row_end/dinv; scatter CSR.
__global__ __launch_bounds__(512) void k_bfinal(const uint_t* __restrict__ tmp,
                                                const int* __restrict__ btot, int N, int nb1,
                                                uint_t* __restrict__ csr,
                                                int* __restrict__ row_ptr,
                                                int* __restrict__ row_end,
                                                float* __restrict__ dinv) {
  __shared__ int ws[8];
  __shared__ int sseg0, sseg1;
  __shared__ uint_t cnt[1 << BSH];
  __shared__ uint_t ppfx[1 << BSH];
  __shared__ uint_t cur[1 << BSH];
  int b = blockIdx.x, t = threadIdx.x;
  {
    int v = (t < nb1) ? btot[t] : 0;
    int incl = blk_scan_incl(v, ws, 8);
    if (t == b) {
      sseg0 = incl - v;
      sseg1 = incl;
    }
  }
  for (int i = t; i < (1 << BSH); i += 512) cnt[i] = 0;
  __syncthreads();
  int seg0 = sseg0, seg1 = sseg1;
  int pb = ((seg0 + 3) & ~3) + BSLACK * b;  // padded, 16B-aligned bucket base
  for (int i = seg0 + t; i < seg1; i += 512) atomicAdd(&cnt[tmp[i] >> 17], 1u);
  __syncthreads();
  if (t < 64) {  // wave 0: scan 512 padded counts, 8 per lane
    uint_t pc[8];
    uint_t s = 0;
#pragma unroll
    for (int k = 0; k < 8; k++) {
      pc[k] = (cnt[t * 8 + k] + 3u) & ~3u;
      s += pc[k];
    }
    int incl = (int)s;
#pragma unroll
    for (int d = 1; d < 64; d <<= 1) {
      int u = __shfl_up(incl, d, 64);
      if (t >= d) incl += u;
    }
    uint_t excl = (uint_t)incl - s;
#pragma unroll
    for (int k = 0; k < 8; k++) {
      ppfx[t * 8 + k] = excl;
      excl += pc[k];
    }
  }
  __syncthreads();
  int nd0 = b << BSH;
  for (int i = t; i < (1 << BSH); i += 512) {
    cur[i] = ppfx[i];
    int g = nd0 + i;
    if (g < N) {
      row_ptr[g] = pb + (int)ppfx[i];
      row_end[g] = pb + (int)(ppfx[i] + ((cnt[i] + 3u) & ~3u));
      dinv[g] = rsqrtf((float)cnt[i] + 1.0f);  // +1 = self-loop
    }
  }
  __syncthreads();
  for (int i = seg0 + t; i < seg1; i += 512) {
    uint_t v = tmp[i];
    uint_t pos = atomicAdd(&cur[v >> 17], 1u);
    csr[pb + (int)pos] = v & 0x1FFFFu;
  }
  __syncthreads();
  for (int i = t; i < (1 << BSH); i += 512) {
    uint_t e0 = cur[i];
    uint_t e1 = ppfx[i] + ((cnt[i] + 3u) & ~3u);
    for (uint_t k = e0; k < e1; k++) csr[pb + (int)k] = (uint_t)N;
  }
}

// ---------------- GEMM 1 (MFMA): xW' = dinv .* (bf16(x) @ bf16(W1)), bf16 out ------------

__global__ __launch_bounds__(256) void k_gemm1(const float* __restrict__ A,
                                               const ushort_t* __restrict__ Wt,
                                               const float* __restrict__ dinv,
                                               ushort_t* __restrict__ C, int n) {
  __shared__ ushort_t Ws[128][132];  // col-major W: Ws[j][k]; stride 264B -> conflict-free b64
  int t = threadIdx.x;
#pragma unroll
  for (int i = 0; i < 16; i++) {
    int f = t + 256 * i;
    int rowj = f >> 5, seg = f & 31;
    *(uint2*)&Ws[rowj][seg * 4] = *(const uint2*)(Wt + rowj * 128 + seg * 4);
  }
  __syncthreads();
  int w = t >> 6, lane = t & 63;
  int rl = lane & 15, g = lane >> 4;
  int row = blockIdx.x * 64 + w * 16 + rl;
  bool valid = row < n;
  const float* Ar = A + (size_t)row * DIN + 4 * g;
  s4v af[8];
#pragma unroll
  for (int kk = 0; kk < 8; kk++) {
    float4 v = make_float4(0.f, 0.f, 0.f, 0.f);
    if (valid) v = *(const float4*)(Ar + kk * 16);
    s4v a;
    a[0] = (short)f2bf(v.x);
    a[1] = (short)f2bf(v.y);
    a[2] = (short)f2bf(v.z);
    a[3] = (short)f2bf(v.w);
    af[kk] = a;
  }
  f4v acc[8];
#pragma unroll
  for (int ct = 0; ct < 8; ct++) acc[ct] = (f4v)0.f;
#pragma unroll
  for (int kk = 0; kk < 8; kk++) {
    int ko = kk * 16 + 4 * g;
#pragma unroll
    for (int ct = 0; ct < 8; ct++) {
      s4v b = *(s4v*)&Ws[ct * 16 + rl][ko];
      acc[ct] = MFMA16(af[kk], b, acc[ct]);
    }
  }
  int gr0 = blockIdx.x * 64 + w * 16 + 4 * g;
#pragma unroll
  for (int i = 0; i < 4; i++) {
    int gr = gr0 + i;
    if (gr < n) {
      float dv = dinv[gr];
#pragma unroll
      for (int ct = 0; ct < 8; ct++)
        C[(size_t)gr * HID + ct * 16 + rl] = f2bf(dv * acc[ct][i]);
    }
  }
}

// ------------- Aggregation over pre-scaled bf16 H' (one wave per node, lane = 2 cols).
// out = dn*(H'[node] + sum H'[src]); mode1: relu(+bias) then prescale by dn for next layer.

__global__ __launch_bounds__(256) void k_agg(const ushort_t* __restrict__ H,
                                             const int* __restrict__ row_ptr,
                                             const int* __restrict__ row_end,
                                             const uint_t* __restrict__ csr,
                                             const float* __restrict__ dinv,
                                             const float* __restrict__ bias,
                                             ushort_t* __restrict__ out, int n,
                                             int prescale_relu) {
  int node = (blockIdx.x * blockDim.x + threadIdx.x) >> 6;
  int lane = threadIdx.x & 63;
  if (node >= n) return;
  const char* Hb = (const char*)H;
  uint_t loff = (uint_t)lane << 2;
  float dn = dinv[node];
  int j = row_ptr[node], end = row_end[node];
  float2 hs = bf2x2(*(const uint_t*)(Hb + ((size_t)(((uint_t)node << 8) | loff))));
  float ax = hs.x, ay = hs.y;  // self term (dn factor applied at end)
  if (j < end) {
    uint4 c = *(const uint4*)(csr + j);
    while (true) {
      int jn = j + 4;
      bool more = jn < end;
      uint4 cn;
      if (more) cn = *(const uint4*)(csr + jn);
      uint_t v0 = *(const uint_t*)(Hb + (size_t)((c.x << 8) | loff));
      uint_t v1 = *(const uint_t*)(Hb + (size_t)((c.y << 8) | loff));
      uint_t v2 = *(const uint_t*)(Hb + (size_t)((c.z << 8) | loff));
      uint_t v3 = *(const uint_t*)(Hb + (size_t)((c.w << 8) | loff));
      float2 f0 = bf2x2(v0), f1 = bf2x2(v1), f2 = bf2x2(v2), f3 = bf2x2(v3);
      ax += f0.x + f1.x;
      ay += f0.y + f1.y;
      ax += f2.x + f3.x;
      ay += f2.y + f3.y;
      if (!more) break;
      c = cn;
      j = jn;
    }
  }
  ax *= dn;
  ay *= dn;
  if (prescale_relu) {
    ax = fmaxf(ax + bias[2 * lane], 0.f) * dn;
    ay = fmaxf(ay + bias[2 * lane + 1], 0.f) * dn;
  }
  ((uint_t*)out)[(size_t)node * 64 + lane] = pack2bf(ax, ay);
}

// ------------- GEMM 2 (MFMA, fused): [mu | logstd] = agg2(bf16) @ Wt2 + b, fp32 out -------

__global__ __launch_bounds__(256) void k_gemm2(const ushort_t* __restrict__ A,
                                               const ushort_t* __restrict__ Wt,
                                               const float* __restrict__ bmu,
                                               const float* __restrict__ bls,
                                               float* __restrict__ out, int n) {
  __shared__ ushort_t Ws[128][132];
  int t = threadIdx.x;
#pragma unroll
  for (int i = 0; i < 16; i++) {
    int f = t + 256 * i;
    int rowj = f >> 5, seg = f & 31;
    *(uint2*)&Ws[rowj][seg * 4] = *(const uint2*)(Wt + rowj * 128 + seg * 4);
  }
  __syncthreads();
  int w = t >> 6, lane = t & 63;
  int rl = lane & 15, g = lane >> 4;
  int row = blockIdx.x * 64 + w * 16 + rl;
  bool valid = row < n;
  const ushort_t* Ar = A + (size_t)row * HID + 4 * g;
  s4v af[8];
#pragma unroll
  for (int kk = 0; kk < 8; kk++) {
    s4v a = (s4v)0;
    if (valid) a = *(const s4v*)(Ar + kk * 16);
    af[kk] = a;
  }
  f4v acc[8];
#pragma unroll
  for (int ct = 0; ct < 8; ct++) acc[ct] = (f4v)0.f;
#pragma unroll
  for (int kk = 0; kk < 8; kk++) {
    int ko = kk * 16 + 4 * g;
#pragma unroll
    for (int ct = 0; ct < 8; ct++) {
      s4v b = *(s4v*)&Ws[ct * 16 + rl][ko];
      acc[ct] = MFMA16(af[kk], b, acc[ct]);
    }
  }
  int gr0 = blockIdx.x * 64 + w * 16 + 4 * g;
#pragma unroll
  for (int ct = 0; ct < 8; ct++) {
    int col = ct * 16 + rl;
    float bv;
    size_t obase;
    int cc;
    if (ct < 4) {
      bv = bmu[col];
      obase = 0;
      cc = col;
    } else {
      bv = bls[col - 64];
      obase = (size_t)n * DOUT;
      cc = col - 64;
    }
#pragma unroll
    for (int i = 0; i < 4; i++) {
      int gr = gr0 + i;
      if (gr < n) out[obase + (size_t)gr * DOUT + cc] = acc[ct][i] + bv;
    }
  }
}

// ---------------- launcher ----------------

extern "C" void kernel_launch(void* const* d_in, const int* in_sizes, int n_in,
                              void* d_out, int out_size, void* d_ws, size_t ws_size,
                              hipStream_t stream) {
  const float* x   = (const float*)d_in[0];
  const int*   ei  = (const int*)d_in[1];
  const float* W1  = (const float*)d_in[2];
  const float* b1  = (const float*)d_in[3];
  const float* Wmu = (const float*)d_in[4];
  const float* bmu = (const float*)d_in[5];
  const float* Wls = (const float*)d_in[6];
  const float* bls = (const float*)d_in[7];
  float* out = (float*)d_out;

  const int N = in_sizes[0] / DIN;
  const int E = in_sizes[1] / 2;
  const int* esrc = ei;
  const int* edst = ei + E;
  const int nb1 = ceil_div(N, 1 << BSH);  // <= 256
  const int CH = ceil_div(E, NCHUNK);

  char* ws = (char*)d_ws;
  size_t off = 0;
  auto alloc = [&](size_t bytes) -> void* {
    void* p = ws + off;
    off = (off + bytes + 255) & ~(size_t)255;
    return p;
  };
  ushort_t* xWb   = (ushort_t*)alloc((size_t)(N + 1) * HID * sizeof(ushort_t));  // gemm1 out / agg2 out
  ushort_t* h     = (ushort_t*)alloc((size_t)(N + 1) * HID * sizeof(ushort_t));
  uint_t* csr     = (uint_t*)alloc(((size_t)E + (size_t)(BSLACK + 8) * nb1 + 16) * 4);
  uint_t* tmp     = (uint_t*)alloc((size_t)E * 4);
  int* counts     = (int*)alloc((size_t)NCHUNK * nb1 * 4);
  int* chunk_off  = (int*)alloc((size_t)NCHUNK * nb1 * 4);
  int* btot       = (int*)alloc((size_t)nb1 * 4);
  int* row_ptr    = (int*)alloc((size_t)N * 4);
  int* row_end    = (int*)alloc((size_t)N * 4);
  float* dinv     = (float*)alloc((size_t)(N + 1) * 4);
  ushort_t* wt1b  = (ushort_t*)alloc((size_t)HID * HID * 2);
  ushort_t* wt2b  = (ushort_t*)alloc((size_t)HID * HID * 2);
  (void)ws_size; (void)n_in; (void)out_size;

  // fused: coarse hist + weight prep + sentinel zeroing
  k_setup<<<NCHUNK + 33, 512, 0, stream>>>(edst, E, CH, nb1, counts, W1, Wmu, Wls, wt1b, wt2b,
                                           xWb, h, dinv, N);
  k_bscan<<<nb1, 256, 0, stream>>>(counts, nb1, chunk_off, btot);
  k_bscatter<<<NCHUNK, 256, 0, stream>>>(esrc, edst, E, CH, nb1, btot, chunk_off, tmp);
  k_bfinal<<<nb1, 512, 0, stream>>>(tmp, btot, N, nb1, csr, row_ptr, row_end, dinv);

  // Layer 1: h' = dinv .* relu(Ahat @ (x@W1) + b1)
  k_gemm1<<<ceil_div(N, 64), 256, 0, stream>>>(x, wt1b, dinv, xWb, N);
  k_agg<<<ceil_div(N, 4), 256, 0, stream>>>(xWb, row_ptr, row_end, csr, dinv, b1, h, N, 1);

  // Layer 2+3: agg2 = Ahat-weighted sum of h' (raw, bf16), then [mu|logstd] = agg2 @ Wt2 + b
  k_agg<<<ceil_div(N, 4), 256, 0, stream>>>(h, row_ptr, row_end, csr, dinv, nullptr, xWb, N, 0);
  k_gemm2<<<ceil_div(N, 64), 256, 0, stream>>>(xWb, wt2b, bmu, bls, out, N);
}